// Round 2
// baseline (251.593 us; speedup 1.0000x reference)
//
#include <hip/hip_runtime.h>

// ---------- small helpers ----------
typedef __attribute__((ext_vector_type(8))) short bf16x8;
typedef __attribute__((ext_vector_type(4))) float f32x4;

typedef const __attribute__((address_space(1))) void* as1cv;
typedef __attribute__((address_space(3))) void* as3v;

__device__ __forceinline__ unsigned short f2bf(float f) {
    union { float f; unsigned u; } x; x.f = f;
    unsigned r = x.u + 0x7FFFu + ((x.u >> 16) & 1u);   // RNE
    return (unsigned short)(r >> 16);
}
__device__ __forceinline__ float bf2f(unsigned short u) {
    union { unsigned u; float f; } x; x.u = ((unsigned)u) << 16; return x.f;
}

// ---------- 1. fp32 -> bf16 convert (vectorized, grid-stride) ----------
__global__ void k_cvt_bf16(const float* __restrict__ in, unsigned short* __restrict__ out, long n) {
    long i = (long)blockIdx.x * blockDim.x + threadIdx.x;
    long stride = (long)gridDim.x * blockDim.x;
    long n4 = n >> 2;
    for (long j = i; j < n4; j += stride) {
        float4 v = ((const float4*)in)[j];
        ushort4 o;
        o.x = f2bf(v.x); o.y = f2bf(v.y); o.z = f2bf(v.z); o.w = f2bf(v.w);
        ((ushort4*)out)[j] = o;
    }
}

// ---------- 2. W (rows x cols, f32) -> Wt (cols x rows, bf16) ----------
__global__ void k_transpose_bf16(const float* __restrict__ W, unsigned short* __restrict__ Wt,
                                 int rows, int cols) {
    __shared__ float tile[64][65];
    int r0 = blockIdx.y * 64, c0 = blockIdx.x * 64;
    #pragma unroll
    for (int i = 0; i < 16; ++i) {
        int idx = threadIdx.x + i * 256;
        int r = idx >> 6, c = idx & 63;
        tile[r][c] = W[(long)(r0 + r) * cols + (c0 + c)];
    }
    __syncthreads();
    #pragma unroll
    for (int i = 0; i < 16; ++i) {
        int idx = threadIdx.x + i * 256;
        int r = idx >> 6, c = idx & 63;
        Wt[(long)(c0 + r) * rows + (r0 + c)] = f2bf(tile[c][r]);
    }
}

// ---------- 3. GEMM: C(MxN) = A(MxK) * Bt(NxK)^T + bias ----------
// 128x128 tile, BK=32, 256 threads (4 waves, 2x2), wave tile 64x64, mfma 16x16x32 bf16
template<int OUT_BF16>
__global__ __launch_bounds__(256, 2) void k_gemm_bt(
    const unsigned short* __restrict__ A,
    const unsigned short* __restrict__ Bt,
    const float* __restrict__ bias,
    void* __restrict__ C,
    int M, int N, int K)
{
    __shared__ unsigned short As[128 * 32];
    __shared__ unsigned short Bs[128 * 32];
    const int tid = threadIdx.x;
    const int nblks = N >> 7;
    const int mblk = blockIdx.x / nblks;
    const int nblk = blockIdx.x - mblk * nblks;
    const long m0 = (long)mblk << 7;
    const long n0 = (long)nblk << 7;
    const int lane = tid & 63, wave = tid >> 6;
    const int wr = wave >> 1, wc = wave & 1;

    // staging: chunk c covers LDS bytes [c*16, c*16+16) = row c/4, col-bytes (c%4)*16
    const int c0 = tid, c1 = tid + 256;
    const unsigned short* Ag0 = A + ((long)(m0 + (c0 >> 2))) * K + ((c0 & 3) << 3);
    const unsigned short* Ag1 = A + ((long)(m0 + (c1 >> 2))) * K + ((c1 & 3) << 3);
    const unsigned short* Bg0 = Bt + ((long)(n0 + (c0 >> 2))) * K + ((c0 & 3) << 3);
    const unsigned short* Bg1 = Bt + ((long)(n0 + (c1 >> 2))) * K + ((c1 & 3) << 3);

    f32x4 acc[4][4];
    #pragma unroll
    for (int i = 0; i < 4; ++i)
        #pragma unroll
        for (int j = 0; j < 4; ++j)
            acc[i][j] = (f32x4){0.f, 0.f, 0.f, 0.f};

    const int kq = lane >> 4, rr = lane & 15;
    const unsigned short* Ap = As + (((wr << 6) + rr) << 5) + (kq << 3);
    const unsigned short* Bp = Bs + (((wc << 6) + rr) << 5) + (kq << 3);

    for (int k0 = 0; k0 < K; k0 += 32) {
        __builtin_amdgcn_global_load_lds((as1cv)(Ag0 + k0), (as3v)(As + c0 * 8), 16, 0, 0);
        __builtin_amdgcn_global_load_lds((as1cv)(Ag1 + k0), (as3v)(As + c1 * 8), 16, 0, 0);
        __builtin_amdgcn_global_load_lds((as1cv)(Bg0 + k0), (as3v)(Bs + c0 * 8), 16, 0, 0);
        __builtin_amdgcn_global_load_lds((as1cv)(Bg1 + k0), (as3v)(Bs + c1 * 8), 16, 0, 0);
        asm volatile("s_waitcnt vmcnt(0)" ::: "memory");
        __syncthreads();

        bf16x8 af[4], bfr[4];
        #pragma unroll
        for (int i = 0; i < 4; ++i) {
            af[i]  = *(const bf16x8*)(Ap + (i << 9));   // +16 rows = +512 elems
            bfr[i] = *(const bf16x8*)(Bp + (i << 9));
        }
        #pragma unroll
        for (int i = 0; i < 4; ++i)
            #pragma unroll
            for (int j = 0; j < 4; ++j)
                acc[i][j] = __builtin_amdgcn_mfma_f32_16x16x32_bf16(af[i], bfr[j], acc[i][j], 0, 0, 0);
        __syncthreads();
    }

    // epilogue: C/D layout col = lane&15, row = (lane>>4)*4 + reg
    const long rowb = m0 + (wr << 6) + (kq << 2);
    const long colb = n0 + (wc << 6) + rr;
    #pragma unroll
    for (int nj = 0; nj < 4; ++nj) {
        const long col = colb + nj * 16;
        const float bv = bias[col];
        #pragma unroll
        for (int mi = 0; mi < 4; ++mi) {
            #pragma unroll
            for (int jj = 0; jj < 4; ++jj) {
                const long row = rowb + mi * 16 + jj;
                float v = acc[mi][nj][jj] + bv;
                if (OUT_BF16) ((unsigned short*)C)[row * N + col] = f2bf(v);
                else          ((float*)C)[row * N + col] = v;
            }
        }
    }
}

// ---------- 4. column sums: total[b][d] = sum_t p[b,t,d] ----------
__global__ void k_colsum(const unsigned short* __restrict__ p, float* __restrict__ total, int T) {
    const int b = blockIdx.y;
    const int t0 = blockIdx.x * 64;
    const int tid = threadIdx.x;
    float s0 = 0.f, s1 = 0.f, s2 = 0.f, s3 = 0.f;
    const unsigned short* base = p + ((long)b * T + t0) * 1024 + tid * 4;
    for (int t = 0; t < 64; ++t) {
        ushort4 v = *(const ushort4*)(base + (long)t * 1024);
        s0 += bf2f(v.x); s1 += bf2f(v.y); s2 += bf2f(v.z); s3 += bf2f(v.w);
    }
    float* tp = total + b * 1024 + tid * 4;
    atomicAdd(tp + 0, s0); atomicAdd(tp + 1, s1);
    atomicAdd(tp + 2, s2); atomicAdd(tp + 3, s3);
}

// ---------- 5. FSMN v2: all-register FIR, no LDS ----------
// block: 64 d's x 32 t's; thread: 1 d, 8 t's. Window + taps in REGISTERS,
// loaded directly from global (coalesced across lanes; taps L1-hot).
// __launch_bounds__(256,2) -> 256-VGPR cap so the ~130 live regs never remat.
__global__ __launch_bounds__(256, 2) void k_fsmn(
    const unsigned short* __restrict__ p,   // (B*T, 1024) bf16
    const float* __restrict__ mw,           // (41, 1024) fp32
    const float* __restrict__ total,        // (B, 1024) fp32
    unsigned short* __restrict__ p2,        // (B*T, 1024) bf16
    int T)
{
    const int b  = blockIdx.z;
    const int t0 = blockIdx.y * 32;
    const int d0 = blockIdx.x * 64;
    const int lane = threadIdx.x & 63;
    const int tg   = threadIdx.x >> 6;
    const int d  = d0 + lane;
    const int tb = t0 + tg * 8;             // first output t for this thread

    // window w[j] = p[b, tb + j - 39, d], j = 0..46  (zero for t<0)
    float w[47];
    #pragma unroll
    for (int j = 0; j < 47; ++j) {
        const int t = tb + j - 39;
        w[j] = (t >= 0) ? bf2f(p[((long)b * T + t) * 1024 + d]) : 0.f;
    }

    // taps (per-d): m[lag] = mw[1+lag][d]; m0 = mw[0][d]
    const float m0v = mw[d];
    float m[40];
    #pragma unroll
    for (int lag = 0; lag < 40; ++lag) m[lag] = mw[(1 + lag) * 1024 + d];

    // band FIR: accb[t] = sum_lag m[lag] * p[tt - lag]
    float accb[8] = {0,0,0,0,0,0,0,0};
    #pragma unroll
    for (int lag = 0; lag < 40; ++lag) {
        #pragma unroll
        for (int t = 0; t < 8; ++t)
            accb[t] = fmaf(m[lag], w[t + 39 - lag], accb[t]);
    }

    // windowed sum via rolling update: accw[t] = sum_{j=t}^{t+39} w[j]
    float accw[8];
    {
        float s = 0.f;
        #pragma unroll
        for (int j = 0; j < 40; ++j) s += w[j];
        accw[0] = s;
        #pragma unroll
        for (int t = 1; t < 8; ++t) accw[t] = accw[t - 1] + w[t + 39] - w[t - 1];
    }

    const float tot = total[b * 1024 + d];
    unsigned short* ob = p2 + ((long)b * T + tb) * 1024 + d;
    #pragma unroll
    for (int t = 0; t < 8; ++t)
        ob[(long)t * 1024] = f2bf(accb[t] + m0v * (tot - accw[t]));
}

// ---------- launch ----------
extern "C" void kernel_launch(void* const* d_in, const int* in_sizes, int n_in,
                              void* d_out, int out_size, void* d_ws, size_t ws_size,
                              hipStream_t stream) {
    const float* x  = (const float*)d_in[0];
    const float* W1 = (const float*)d_in[1];
    const float* b1 = (const float*)d_in[2];
    const float* W2 = (const float*)d_in[3];
    const float* b2 = (const float*)d_in[4];
    const float* mw = (const float*)d_in[5];
    float* out = (float*)d_out;

    const int B = 8, T = 2048;
    const long M = (long)B * T;          // 16384 rows
    const int N = 1024, K = 1024;

    // ws layout:
    // [0, 32MB)        x_bf   (reused as p2_bf after GEMM1 consumed x_bf)
    // [32MB, 34MB)     W1t
    // [34MB, 36MB)     W2t
    // [36MB, 68MB)     p_bf
    // [68MB, +32KB)    totals
    char* ws = (char*)d_ws;
    unsigned short* x_bf   = (unsigned short*)(ws);
    unsigned short* W1t    = (unsigned short*)(ws + 33554432L);
    unsigned short* W2t    = (unsigned short*)(ws + 35651584L);
    unsigned short* p_bf   = (unsigned short*)(ws + 37748736L);
    float*          totals = (float*)(ws + 71303168L);
    unsigned short* p2_bf  = x_bf;

    k_cvt_bf16<<<2048, 256, 0, stream>>>(x, x_bf, M * 1024);

    dim3 tgrid(16, 16);
    k_transpose_bf16<<<tgrid, 256, 0, stream>>>(W1, W1t, K, N);
    k_transpose_bf16<<<tgrid, 256, 0, stream>>>(W2, W2t, K, N);

    k_gemm_bt<1><<<dim3((int)((M / 128) * (N / 128))), 256, 0, stream>>>(
        x_bf, W1t, b1, (void*)p_bf, (int)M, N, K);

    hipMemsetAsync(totals, 0, B * 1024 * sizeof(float), stream);
    k_colsum<<<dim3(T / 64, B), 256, 0, stream>>>(p_bf, totals, T);

    k_fsmn<<<dim3(1024 / 64, T / 32, B), 256, 0, stream>>>(p_bf, mw, totals, p2_bf, T);

    k_gemm_bt<0><<<dim3((int)((M / 128) * (N / 128))), 256, 0, stream>>>(
        p2_bf, W2t, b2, (void*)out, (int)M, N, K);
}

// Round 3
// 176.715 us; speedup vs baseline: 1.4237x; 1.4237x over previous
//
#include <hip/hip_runtime.h>

// ---------- small helpers ----------
typedef __attribute__((ext_vector_type(8))) short bf16x8;
typedef __attribute__((ext_vector_type(4))) float f32x4;

typedef const __attribute__((address_space(1))) void* as1cv;
typedef __attribute__((address_space(3))) void* as3v;

__device__ __forceinline__ unsigned short f2bf(float f) {
    union { float f; unsigned u; } x; x.f = f;
    unsigned r = x.u + 0x7FFFu + ((x.u >> 16) & 1u);   // RNE
    return (unsigned short)(r >> 16);
}
__device__ __forceinline__ float bf2f(unsigned short u) {
    union { unsigned u; float f; } x; x.u = ((unsigned)u) << 16; return x.f;
}

// ---------- 1. fp32 -> bf16 convert (vectorized, grid-stride) ----------
__global__ void k_cvt_bf16(const float* __restrict__ in, unsigned short* __restrict__ out, long n) {
    long i = (long)blockIdx.x * blockDim.x + threadIdx.x;
    long stride = (long)gridDim.x * blockDim.x;
    long n4 = n >> 2;
    for (long j = i; j < n4; j += stride) {
        float4 v = ((const float4*)in)[j];
        ushort4 o;
        o.x = f2bf(v.x); o.y = f2bf(v.y); o.z = f2bf(v.z); o.w = f2bf(v.w);
        ((ushort4*)out)[j] = o;
    }
}

// ---------- 2. W (rows x cols, f32) -> Wt (cols x rows, bf16) ----------
__global__ void k_transpose_bf16(const float* __restrict__ W, unsigned short* __restrict__ Wt,
                                 int rows, int cols) {
    __shared__ float tile[64][65];
    int r0 = blockIdx.y * 64, c0 = blockIdx.x * 64;
    #pragma unroll
    for (int i = 0; i < 16; ++i) {
        int idx = threadIdx.x + i * 256;
        int r = idx >> 6, c = idx & 63;
        tile[r][c] = W[(long)(r0 + r) * cols + (c0 + c)];
    }
    __syncthreads();
    #pragma unroll
    for (int i = 0; i < 16; ++i) {
        int idx = threadIdx.x + i * 256;
        int r = idx >> 6, c = idx & 63;
        Wt[(long)(c0 + r) * rows + (r0 + c)] = f2bf(tile[c][r]);
    }
}

// ---------- 3. GEMM: C(MxN) = A(MxK) * Bt(NxK)^T + bias ----------
// 128x128 tile, BK=32, 256 threads (4 waves, 2x2), wave tile 64x64, mfma 16x16x32 bf16
template<int OUT_BF16>
__global__ __launch_bounds__(256, 2) void k_gemm_bt(
    const unsigned short* __restrict__ A,
    const unsigned short* __restrict__ Bt,
    const float* __restrict__ bias,
    void* __restrict__ C,
    int M, int N, int K)
{
    __shared__ unsigned short As[128 * 32];
    __shared__ unsigned short Bs[128 * 32];
    const int tid = threadIdx.x;
    const int nblks = N >> 7;
    const int mblk = blockIdx.x / nblks;
    const int nblk = blockIdx.x - mblk * nblks;
    const long m0 = (long)mblk << 7;
    const long n0 = (long)nblk << 7;
    const int lane = tid & 63, wave = tid >> 6;
    const int wr = wave >> 1, wc = wave & 1;

    const int c0 = tid, c1 = tid + 256;
    const unsigned short* Ag0 = A + ((long)(m0 + (c0 >> 2))) * K + ((c0 & 3) << 3);
    const unsigned short* Ag1 = A + ((long)(m0 + (c1 >> 2))) * K + ((c1 & 3) << 3);
    const unsigned short* Bg0 = Bt + ((long)(n0 + (c0 >> 2))) * K + ((c0 & 3) << 3);
    const unsigned short* Bg1 = Bt + ((long)(n0 + (c1 >> 2))) * K + ((c1 & 3) << 3);

    f32x4 acc[4][4];
    #pragma unroll
    for (int i = 0; i < 4; ++i)
        #pragma unroll
        for (int j = 0; j < 4; ++j)
            acc[i][j] = (f32x4){0.f, 0.f, 0.f, 0.f};

    const int kq = lane >> 4, rr = lane & 15;
    const unsigned short* Ap = As + (((wr << 6) + rr) << 5) + (kq << 3);
    const unsigned short* Bp = Bs + (((wc << 6) + rr) << 5) + (kq << 3);

    for (int k0 = 0; k0 < K; k0 += 32) {
        __builtin_amdgcn_global_load_lds((as1cv)(Ag0 + k0), (as3v)(As + c0 * 8), 16, 0, 0);
        __builtin_amdgcn_global_load_lds((as1cv)(Ag1 + k0), (as3v)(As + c1 * 8), 16, 0, 0);
        __builtin_amdgcn_global_load_lds((as1cv)(Bg0 + k0), (as3v)(Bs + c0 * 8), 16, 0, 0);
        __builtin_amdgcn_global_load_lds((as1cv)(Bg1 + k0), (as3v)(Bs + c1 * 8), 16, 0, 0);
        asm volatile("s_waitcnt vmcnt(0)" ::: "memory");
        __syncthreads();

        bf16x8 af[4], bfr[4];
        #pragma unroll
        for (int i = 0; i < 4; ++i) {
            af[i]  = *(const bf16x8*)(Ap + (i << 9));
            bfr[i] = *(const bf16x8*)(Bp + (i << 9));
        }
        #pragma unroll
        for (int i = 0; i < 4; ++i)
            #pragma unroll
            for (int j = 0; j < 4; ++j)
                acc[i][j] = __builtin_amdgcn_mfma_f32_16x16x32_bf16(af[i], bfr[j], acc[i][j], 0, 0, 0);
        __syncthreads();
    }

    const long rowb = m0 + (wr << 6) + (kq << 2);
    const long colb = n0 + (wc << 6) + rr;
    #pragma unroll
    for (int nj = 0; nj < 4; ++nj) {
        const long col = colb + nj * 16;
        const float bv = bias[col];
        #pragma unroll
        for (int mi = 0; mi < 4; ++mi) {
            #pragma unroll
            for (int jj = 0; jj < 4; ++jj) {
                const long row = rowb + mi * 16 + jj;
                float v = acc[mi][nj][jj] + bv;
                if (OUT_BF16) ((unsigned short*)C)[row * N + col] = f2bf(v);
                else          ((float*)C)[row * N + col] = v;
            }
        }
    }
}

// ---------- 4. column sums: total[b][d] = sum_t p[b,t,d] ----------
__global__ void k_colsum(const unsigned short* __restrict__ p, float* __restrict__ total, int T) {
    const int b = blockIdx.y;
    const int t0 = blockIdx.x * 64;
    const int tid = threadIdx.x;
    float s0 = 0.f, s1 = 0.f, s2 = 0.f, s3 = 0.f;
    const unsigned short* base = p + ((long)b * T + t0) * 1024 + tid * 4;
    for (int t = 0; t < 64; ++t) {
        ushort4 v = *(const ushort4*)(base + (long)t * 1024);
        s0 += bf2f(v.x); s1 += bf2f(v.y); s2 += bf2f(v.z); s3 += bf2f(v.w);
    }
    float* tp = total + b * 1024 + tid * 4;
    atomicAdd(tp + 0, s0); atomicAdd(tp + 1, s1);
    atomicAdd(tp + 2, s2); atomicAdd(tp + 3, s3);
}

// ---------- 5. FSMN v3: transposed-LDS window, lazy sliding lag loop ----------
// block: 64 d x 32 t, 256 threads; thread: 1 d (=lane), 8 t's.
// LDS spT[d][c], stride 73 dwords (odd => conflict-free for stride-73 lane
// access on both the transpose write and the per-thread window reads).
// Lag loop loads ONE new window value per lag (sliding 8-value live window)
// plus one L2-hot tap, so register pressure stays ~60 and latency is LDS-class.
#define SP_STRIDE 73
__global__ __launch_bounds__(256, 2) void k_fsmn(
    const unsigned short* __restrict__ p,   // (B*T, 1024) bf16
    const float* __restrict__ mw,           // (41, 1024) fp32
    const float* __restrict__ total,        // (B, 1024) fp32
    unsigned short* __restrict__ p2,        // (B*T, 1024) bf16
    int T)
{
    __shared__ float spT[64 * SP_STRIDE];   // [d][c], c = t - (t0-39), 71 cols used
    const int b  = blockIdx.z;
    const int t0 = blockIdx.y * 32;
    const int d0 = blockIdx.x * 64;
    const int tid = threadIdx.x;

    // stage transposed: spT[d][c] = p[b, t0+c-39, d0+d]  (0 for t<0)
    for (int i = 0; i < 18; ++i) {
        int idx = tid + i * 256;
        if (idx < 71 * 64) {
            int c = idx >> 6, dcol = idx & 63;
            int t = t0 + c - 39;
            float v = 0.f;
            if (t >= 0) v = bf2f(p[((long)b * T + t) * 1024 + d0 + dcol]);
            spT[dcol * SP_STRIDE + c] = v;
        }
    }
    __syncthreads();

    const int lane = tid & 63, tg = tid >> 6;
    const int d  = d0 + lane;
    const int tb = t0 + tg * 8;
    const float* wp = spT + lane * SP_STRIDE + tg * 8;   // wp[j] = w[j] = p[tb+j-39]

    // preload high edge w[40..46] (kept live for rolling window-sum)
    float w[47];
    #pragma unroll
    for (int j = 40; j < 47; ++j) w[j] = wp[j];
    float S_hi = ((w[40] + w[41]) + (w[42] + w[43])) + ((w[44] + w[45]) + w[46]);
    float S_all = S_hi;

    float acc[8] = {0,0,0,0,0,0,0,0};
    #pragma unroll
    for (int lag = 0; lag < 40; ++lag) {
        const int jn = 39 - lag;            // new window value this lag
        w[jn] = wp[jn];
        S_all += w[jn];
        const float m = mw[(1 + lag) * 1024 + d];
        #pragma unroll
        for (int t = 0; t < 8; ++t)
            acc[t] = fmaf(m, w[t + jn], acc[t]);
    }

    // accw[t] = sum_{j=t}^{t+39} w[j], rolling from accw[0] = S_all - S_hi
    float accw[8];
    accw[0] = S_all - S_hi;
    #pragma unroll
    for (int t = 1; t < 8; ++t) accw[t] = accw[t - 1] + w[t + 39] - w[t - 1];

    const float m0v = mw[d];
    const float tot = total[b * 1024 + d];
    unsigned short* ob = p2 + ((long)b * T + tb) * 1024 + d;
    #pragma unroll
    for (int t = 0; t < 8; ++t)
        ob[(long)t * 1024] = f2bf(acc[t] + m0v * (tot - accw[t]));
}

// ---------- launch ----------
extern "C" void kernel_launch(void* const* d_in, const int* in_sizes, int n_in,
                              void* d_out, int out_size, void* d_ws, size_t ws_size,
                              hipStream_t stream) {
    const float* x  = (const float*)d_in[0];
    const float* W1 = (const float*)d_in[1];
    const float* b1 = (const float*)d_in[2];
    const float* W2 = (const float*)d_in[3];
    const float* b2 = (const float*)d_in[4];
    const float* mw = (const float*)d_in[5];
    float* out = (float*)d_out;

    const int B = 8, T = 2048;
    const long M = (long)B * T;          // 16384 rows
    const int N = 1024, K = 1024;

    char* ws = (char*)d_ws;
    unsigned short* x_bf   = (unsigned short*)(ws);
    unsigned short* W1t    = (unsigned short*)(ws + 33554432L);
    unsigned short* W2t    = (unsigned short*)(ws + 35651584L);
    unsigned short* p_bf   = (unsigned short*)(ws + 37748736L);
    float*          totals = (float*)(ws + 71303168L);
    unsigned short* p2_bf  = x_bf;

    k_cvt_bf16<<<2048, 256, 0, stream>>>(x, x_bf, M * 1024);

    dim3 tgrid(16, 16);
    k_transpose_bf16<<<tgrid, 256, 0, stream>>>(W1, W1t, K, N);
    k_transpose_bf16<<<tgrid, 256, 0, stream>>>(W2, W2t, K, N);

    k_gemm_bt<1><<<dim3((int)((M / 128) * (N / 128))), 256, 0, stream>>>(
        x_bf, W1t, b1, (void*)p_bf, (int)M, N, K);

    hipMemsetAsync(totals, 0, B * 1024 * sizeof(float), stream);
    k_colsum<<<dim3(T / 64, B), 256, 0, stream>>>(p_bf, totals, T);

    k_fsmn<<<dim3(1024 / 64, T / 32, B), 256, 0, stream>>>(p_bf, mw, totals, p2_bf, T);

    k_gemm_bt<0><<<dim3((int)((M / 128) * (N / 128))), 256, 0, stream>>>(
        p2_bf, W2t, b2, (void*)out, (int)M, N, K);
}

// Round 4
// 150.149 us; speedup vs baseline: 1.6756x; 1.1769x over previous
//
#include <hip/hip_runtime.h>

// ---------- small helpers ----------
typedef __attribute__((ext_vector_type(8))) short bf16x8;
typedef __attribute__((ext_vector_type(4))) float f32x4;

typedef const __attribute__((address_space(1))) void* as1cv;
typedef __attribute__((address_space(3))) void* as3v;

__device__ __forceinline__ unsigned short f2bf(float f) {
    union { float f; unsigned u; } x; x.f = f;
    unsigned r = x.u + 0x7FFFu + ((x.u >> 16) & 1u);   // RNE
    return (unsigned short)(r >> 16);
}
__device__ __forceinline__ float bf2f(unsigned short u) {
    union { unsigned u; float f; } x; x.u = ((unsigned)u) << 16; return x.f;
}

// ---------- 1. fp32 -> bf16 convert (vectorized, grid-stride) ----------
__global__ void k_cvt_bf16(const float* __restrict__ in, unsigned short* __restrict__ out, long n) {
    long i = (long)blockIdx.x * blockDim.x + threadIdx.x;
    long stride = (long)gridDim.x * blockDim.x;
    long n4 = n >> 2;
    for (long j = i; j < n4; j += stride) {
        float4 v = ((const float4*)in)[j];
        ushort4 o;
        o.x = f2bf(v.x); o.y = f2bf(v.y); o.z = f2bf(v.z); o.w = f2bf(v.w);
        ((ushort4*)out)[j] = o;
    }
}

// ---------- 2. W (rows x cols, f32) -> Wt (cols x rows, bf16) ----------
__global__ void k_transpose_bf16(const float* __restrict__ W, unsigned short* __restrict__ Wt,
                                 int rows, int cols) {
    __shared__ float tile[64][65];
    int r0 = blockIdx.y * 64, c0 = blockIdx.x * 64;
    #pragma unroll
    for (int i = 0; i < 16; ++i) {
        int idx = threadIdx.x + i * 256;
        int r = idx >> 6, c = idx & 63;
        tile[r][c] = W[(long)(r0 + r) * cols + (c0 + c)];
    }
    __syncthreads();
    #pragma unroll
    for (int i = 0; i < 16; ++i) {
        int idx = threadIdx.x + i * 256;
        int r = idx >> 6, c = idx & 63;
        Wt[(long)(c0 + r) * rows + (r0 + c)] = f2bf(tile[c][r]);
    }
}

// ---------- 3. GEMM 256x256 8-phase (T1+T2+T3+T4+T5), BK=64, 8 waves ----------
// C(MxN) = A(MxK) * Bt(NxK)^T + bias.  LDS 128KiB: [buf][slot][8192] ushort,
// slot 0/1 = A half 0/1 (rows 0-127 / 128-255 of tile), slot 2/3 = B halves.
// Swizzle: tile byte a -> a ^ (((a>>7)&7)<<4) (involution, 16B-chunk-preserving);
// applied as pre-swizzled GLOBAL source (linear global_load_lds dest) + swizzled
// ds_read address.  Counted vmcnt(4) at phases 4/8 only; raw s_barrier.
template<int OUT_BF16>
__global__ __launch_bounds__(512, 2) void k_gemm256(
    const unsigned short* __restrict__ A,
    const unsigned short* __restrict__ Bt,
    const float* __restrict__ bias,
    void* __restrict__ C,
    int M, int N, int K)
{
    __shared__ unsigned short lds[2][4][8192];
    const int tid  = threadIdx.x;
    const int lane = tid & 63;
    const int w    = tid >> 6;          // wave 0..7
    const int wm   = w >> 2;            // 0..1 (M half)
    const int wn   = w & 3;             // 0..3 (N quarter)

    // XCD-chunked bijective swizzle (nwg % 8 == 0 here: 256)
    const int nwg = gridDim.x;
    const int cpx = nwg >> 3;
    const int wg  = (blockIdx.x & 7) * cpx + (blockIdx.x >> 3);
    const int nblks = N >> 8;
    const int mblk = wg / nblks, nblk = wg % nblks;
    const long m0 = (long)mblk << 8, n0 = (long)nblk << 8;

    // staging geometry: seg s (0..15) = 1KB = 8 rows x 128B; lane covers 16B
    const int segRow  = lane >> 3;                              // 0..7
    const long segColE = (long)(((lane & 7) ^ segRow) << 3);    // pre-swizzled col (elems)

    // fragment-read geometry
    const int rr = lane & 15, cc = lane >> 4;
    const int smask = (rr & 7) << 4;                            // byte-XOR mask
    const int colSwz0 = (((cc * 16) ^ smask) >> 1);             // ushort units
    const int colSwz1 = (((64 + cc * 16) ^ smask) >> 1);

    // stage one half-tile (128 rows x 64 cols bf16 = 16KB) : 2 gloads/thread
    auto stage = [&](int buf, int slot, const unsigned short* src, long rowBase, int kt) {
        #pragma unroll
        for (int g = 0; g < 2; ++g) {
            const int s = w + g * 8;
            const unsigned short* gp = src + (rowBase + s * 8 + segRow) * (long)K
                                           + (long)kt * 64 + segColE;
            __builtin_amdgcn_global_load_lds((as1cv)gp,
                (as3v)(&lds[buf][slot][s * 512 + lane * 8]), 16, 0, 0);
        }
    };

    f32x4 acc[8][4];
    #pragma unroll
    for (int i = 0; i < 8; ++i)
        #pragma unroll
        for (int j = 0; j < 4; ++j)
            acc[i][j] = (f32x4){0.f, 0.f, 0.f, 0.f};

    bf16x8 bfrag[4][2];
    const int bRowBase = (wn & 1) * 64;
    const int NK = K >> 6;            // 16
    const int ITERS = K >> 7;         // 8

#define VM4   asm volatile("s_waitcnt vmcnt(4)" ::: "memory")
#define PHASE(BUF, Q, STAGES, VMW) do {                                              \
    bf16x8 af0_0, af0_1, af1_0, af1_1;                                               \
    { const unsigned short* Ah = &lds[BUF][wm][0];                                   \
      af0_0 = *(const bf16x8*)(Ah + ((Q)*32 + rr) * 64 + colSwz0);                   \
      af0_1 = *(const bf16x8*)(Ah + ((Q)*32 + rr) * 64 + colSwz1);                   \
      af1_0 = *(const bf16x8*)(Ah + ((Q)*32 + 16 + rr) * 64 + colSwz0);              \
      af1_1 = *(const bf16x8*)(Ah + ((Q)*32 + 16 + rr) * 64 + colSwz1); }            \
    if ((Q) == 0) { const unsigned short* Bh = &lds[BUF][2 + (wn >> 1)][0];          \
      _Pragma("unroll")                                                              \
      for (int nj = 0; nj < 4; ++nj) {                                               \
        bfrag[nj][0] = *(const bf16x8*)(Bh + (bRowBase + nj*16 + rr) * 64 + colSwz0);\
        bfrag[nj][1] = *(const bf16x8*)(Bh + (bRowBase + nj*16 + rr) * 64 + colSwz1);\
      } }                                                                            \
    STAGES;                                                                          \
    VMW;                                                                             \
    __builtin_amdgcn_s_barrier();                                                    \
    asm volatile("s_waitcnt lgkmcnt(0)" ::: "memory");                               \
    __builtin_amdgcn_sched_barrier(0);                                               \
    __builtin_amdgcn_s_setprio(1);                                                   \
    _Pragma("unroll")                                                                \
    for (int nj = 0; nj < 4; ++nj) {                                                 \
      acc[2*(Q)][nj]   = __builtin_amdgcn_mfma_f32_16x16x32_bf16(af0_0, bfrag[nj][0], acc[2*(Q)][nj],   0,0,0); \
      acc[2*(Q)][nj]   = __builtin_amdgcn_mfma_f32_16x16x32_bf16(af0_1, bfrag[nj][1], acc[2*(Q)][nj],   0,0,0); \
      acc[2*(Q)+1][nj] = __builtin_amdgcn_mfma_f32_16x16x32_bf16(af1_0, bfrag[nj][0], acc[2*(Q)+1][nj], 0,0,0); \
      acc[2*(Q)+1][nj] = __builtin_amdgcn_mfma_f32_16x16x32_bf16(af1_1, bfrag[nj][1], acc[2*(Q)+1][nj], 0,0,0); \
    }                                                                                \
    __builtin_amdgcn_s_setprio(0);                                                   \
    __builtin_amdgcn_s_barrier();                                                    \
} while (0)

    // prologue: kt0 all 4 halves + kt1 B halves; retire kt0, keep kt1.B in flight
    stage(0, 0, A,  m0,       0);
    stage(0, 1, A,  m0 + 128, 0);
    stage(0, 2, Bt, n0,       0);
    stage(0, 3, Bt, n0 + 128, 0);
    stage(1, 2, Bt, n0,       1);
    stage(1, 3, Bt, n0 + 128, 1);
    VM4;
    __builtin_amdgcn_s_barrier();

    for (int it = 0; it < ITERS; ++it) {
        const int kt1 = 2 * it + 1;
        int kt2 = 2 * it + 2; if (kt2 >= NK) kt2 = 0;
        int kt3 = 2 * it + 3; if (kt3 >= NK) kt3 = 1;

        PHASE(0, 0, stage(1, 0, A,  m0,       kt1), );
        PHASE(0, 1, stage(1, 1, A,  m0 + 128, kt1), );
        PHASE(0, 2, { stage(0, 2, Bt, n0, kt2); stage(0, 3, Bt, n0 + 128, kt2); }, );
        PHASE(0, 3, , VM4);
        PHASE(1, 0, stage(0, 0, A,  m0,       kt2), );
        PHASE(1, 1, stage(0, 1, A,  m0 + 128, kt2), );
        PHASE(1, 2, { stage(1, 2, Bt, n0, kt3); stage(1, 3, Bt, n0 + 128, kt3); }, );
        PHASE(1, 3, , VM4);
    }
#undef PHASE
#undef VM4

    // epilogue: C/D layout col = lane&15 (rr), row = cc*4 + jj within 16x16 frag
    #pragma unroll
    for (int mi = 0; mi < 8; ++mi) {
        const long rowb = m0 + wm * 128 + mi * 16 + cc * 4;
        #pragma unroll
        for (int nj = 0; nj < 4; ++nj) {
            const long col = n0 + wn * 64 + nj * 16 + rr;
            const float bv = bias[col];
            #pragma unroll
            for (int jj = 0; jj < 4; ++jj) {
                const float v = acc[mi][nj][jj] + bv;
                if (OUT_BF16) ((unsigned short*)C)[(rowb + jj) * N + col] = f2bf(v);
                else          ((float*)C)[(rowb + jj) * N + col] = v;
            }
        }
    }
}

// ---------- 4. column sums: total[b][d] = sum_t p[b,t,d] ----------
__global__ void k_colsum(const unsigned short* __restrict__ p, float* __restrict__ total, int T) {
    const int b = blockIdx.y;
    const int t0 = blockIdx.x * 64;
    const int tid = threadIdx.x;
    float s0 = 0.f, s1 = 0.f, s2 = 0.f, s3 = 0.f;
    const unsigned short* base = p + ((long)b * T + t0) * 1024 + tid * 4;
    for (int t = 0; t < 64; ++t) {
        ushort4 v = *(const ushort4*)(base + (long)t * 1024);
        s0 += bf2f(v.x); s1 += bf2f(v.y); s2 += bf2f(v.z); s3 += bf2f(v.w);
    }
    float* tp = total + b * 1024 + tid * 4;
    atomicAdd(tp + 0, s0); atomicAdd(tp + 1, s1);
    atomicAdd(tp + 2, s2); atomicAdd(tp + 3, s3);
}

// ---------- 5. FSMN v3: transposed-LDS window, lazy sliding lag loop ----------
#define SP_STRIDE 73
__global__ __launch_bounds__(256, 2) void k_fsmn(
    const unsigned short* __restrict__ p,   // (B*T, 1024) bf16
    const float* __restrict__ mw,           // (41, 1024) fp32
    const float* __restrict__ total,        // (B, 1024) fp32
    unsigned short* __restrict__ p2,        // (B*T, 1024) bf16
    int T)
{
    __shared__ float spT[64 * SP_STRIDE];   // [d][c], c = t - (t0-39), 71 cols used
    const int b  = blockIdx.z;
    const int t0 = blockIdx.y * 32;
    const int d0 = blockIdx.x * 64;
    const int tid = threadIdx.x;

    for (int i = 0; i < 18; ++i) {
        int idx = tid + i * 256;
        if (idx < 71 * 64) {
            int c = idx >> 6, dcol = idx & 63;
            int t = t0 + c - 39;
            float v = 0.f;
            if (t >= 0) v = bf2f(p[((long)b * T + t) * 1024 + d0 + dcol]);
            spT[dcol * SP_STRIDE + c] = v;
        }
    }
    __syncthreads();

    const int lane = tid & 63, tg = tid >> 6;
    const int d  = d0 + lane;
    const int tb = t0 + tg * 8;
    const float* wp = spT + lane * SP_STRIDE + tg * 8;   // wp[j] = p[tb+j-39]

    float w[47];
    #pragma unroll
    for (int j = 40; j < 47; ++j) w[j] = wp[j];
    float S_hi = ((w[40] + w[41]) + (w[42] + w[43])) + ((w[44] + w[45]) + w[46]);
    float S_all = S_hi;

    float acc[8] = {0,0,0,0,0,0,0,0};
    #pragma unroll
    for (int lag = 0; lag < 40; ++lag) {
        const int jn = 39 - lag;
        w[jn] = wp[jn];
        S_all += w[jn];
        const float m = mw[(1 + lag) * 1024 + d];
        #pragma unroll
        for (int t = 0; t < 8; ++t)
            acc[t] = fmaf(m, w[t + jn], acc[t]);
    }

    float accw[8];
    accw[0] = S_all - S_hi;
    #pragma unroll
    for (int t = 1; t < 8; ++t) accw[t] = accw[t - 1] + w[t + 39] - w[t - 1];

    const float m0v = mw[d];
    const float tot = total[b * 1024 + d];
    unsigned short* ob = p2 + ((long)b * T + tb) * 1024 + d;
    #pragma unroll
    for (int t = 0; t < 8; ++t)
        ob[(long)t * 1024] = f2bf(acc[t] + m0v * (tot - accw[t]));
}

// ---------- launch ----------
extern "C" void kernel_launch(void* const* d_in, const int* in_sizes, int n_in,
                              void* d_out, int out_size, void* d_ws, size_t ws_size,
                              hipStream_t stream) {
    const float* x  = (const float*)d_in[0];
    const float* W1 = (const float*)d_in[1];
    const float* b1 = (const float*)d_in[2];
    const float* W2 = (const float*)d_in[3];
    const float* b2 = (const float*)d_in[4];
    const float* mw = (const float*)d_in[5];
    float* out = (float*)d_out;

    const int B = 8, T = 2048;
    const long M = (long)B * T;          // 16384 rows
    const int N = 1024, K = 1024;

    char* ws = (char*)d_ws;
    unsigned short* x_bf   = (unsigned short*)(ws);
    unsigned short* W1t    = (unsigned short*)(ws + 33554432L);
    unsigned short* W2t    = (unsigned short*)(ws + 35651584L);
    unsigned short* p_bf   = (unsigned short*)(ws + 37748736L);
    float*          totals = (float*)(ws + 71303168L);
    unsigned short* p2_bf  = x_bf;

    k_cvt_bf16<<<2048, 256, 0, stream>>>(x, x_bf, M * 1024);

    dim3 tgrid(16, 16);
    k_transpose_bf16<<<tgrid, 256, 0, stream>>>(W1, W1t, K, N);
    k_transpose_bf16<<<tgrid, 256, 0, stream>>>(W2, W2t, K, N);

    k_gemm256<1><<<dim3((int)((M / 256) * (N / 256))), 512, 0, stream>>>(
        x_bf, W1t, b1, (void*)p_bf, (int)M, N, K);

    hipMemsetAsync(totals, 0, B * 1024 * sizeof(float), stream);
    k_colsum<<<dim3(T / 64, B), 256, 0, stream>>>(p_bf, totals, T);

    k_fsmn<<<dim3(1024 / 64, T / 32, B), 256, 0, stream>>>(p_bf, mw, totals, p2_bf, T);

    k_gemm256<0><<<dim3((int)((M / 256) * (N / 256))), 512, 0, stream>>>(
        p2_bf, W2t, b2, (void*)out, (int)M, N, K);
}

// Round 5
// 137.699 us; speedup vs baseline: 1.8271x; 1.0904x over previous
//
#include <hip/hip_runtime.h>

// ---------- small helpers ----------
typedef __attribute__((ext_vector_type(8))) short bf16x8;
typedef __attribute__((ext_vector_type(4))) float f32x4;
typedef __attribute__((ext_vector_type(8))) unsigned short u16x8;

typedef const __attribute__((address_space(1))) void* as1cv;
typedef __attribute__((address_space(3))) void* as3v;

__device__ __forceinline__ unsigned short f2bf(float f) {
    union { float f; unsigned u; } x; x.f = f;
    unsigned r = x.u + 0x7FFFu + ((x.u >> 16) & 1u);   // RNE
    return (unsigned short)(r >> 16);
}
__device__ __forceinline__ float bf2f(unsigned short u) {
    union { unsigned u; float f; } x; x.u = ((unsigned)u) << 16; return x.f;
}

// ---------- 1. fp32 -> bf16 convert (vectorized, grid-stride) ----------
__global__ void k_cvt_bf16(const float* __restrict__ in, unsigned short* __restrict__ out, long n) {
    long i = (long)blockIdx.x * blockDim.x + threadIdx.x;
    long stride = (long)gridDim.x * blockDim.x;
    long n4 = n >> 2;
    for (long j = i; j < n4; j += stride) {
        float4 v = ((const float4*)in)[j];
        ushort4 o;
        o.x = f2bf(v.x); o.y = f2bf(v.y); o.z = f2bf(v.z); o.w = f2bf(v.w);
        ((ushort4*)out)[j] = o;
    }
}

// ---------- 2. W (rows x cols, f32) -> Wt (cols x rows, bf16) ----------
__global__ void k_transpose_bf16(const float* __restrict__ W, unsigned short* __restrict__ Wt,
                                 int rows, int cols) {
    __shared__ float tile[64][65];
    int r0 = blockIdx.y * 64, c0 = blockIdx.x * 64;
    #pragma unroll
    for (int i = 0; i < 16; ++i) {
        int idx = threadIdx.x + i * 256;
        int r = idx >> 6, c = idx & 63;
        tile[r][c] = W[(long)(r0 + r) * cols + (c0 + c)];
    }
    __syncthreads();
    #pragma unroll
    for (int i = 0; i < 16; ++i) {
        int idx = threadIdx.x + i * 256;
        int r = idx >> 6, c = idx & 63;
        Wt[(long)(c0 + r) * rows + (r0 + c)] = f2bf(tile[c][r]);
    }
}

// ---------- 3. GEMM 256x256 8-phase (T1+T2+T3+T4+T5), BK=64, 8 waves ----------
template<int OUT_BF16>
__global__ __launch_bounds__(512, 2) void k_gemm256(
    const unsigned short* __restrict__ A,
    const unsigned short* __restrict__ Bt,
    const float* __restrict__ bias,
    void* __restrict__ C,
    int M, int N, int K)
{
    __shared__ unsigned short lds[2][4][8192];
    const int tid  = threadIdx.x;
    const int lane = tid & 63;
    const int w    = tid >> 6;          // wave 0..7
    const int wm   = w >> 2;            // 0..1 (M half)
    const int wn   = w & 3;             // 0..3 (N quarter)

    const int nwg = gridDim.x;
    const int cpx = nwg >> 3;
    const int wg  = (blockIdx.x & 7) * cpx + (blockIdx.x >> 3);
    const int nblks = N >> 8;
    const int mblk = wg / nblks, nblk = wg % nblks;
    const long m0 = (long)mblk << 8, n0 = (long)nblk << 8;

    const int segRow  = lane >> 3;
    const long segColE = (long)(((lane & 7) ^ segRow) << 3);

    const int rr = lane & 15, cc = lane >> 4;
    const int smask = (rr & 7) << 4;
    const int colSwz0 = (((cc * 16) ^ smask) >> 1);
    const int colSwz1 = (((64 + cc * 16) ^ smask) >> 1);

    auto stage = [&](int buf, int slot, const unsigned short* src, long rowBase, int kt) {
        #pragma unroll
        for (int g = 0; g < 2; ++g) {
            const int s = w + g * 8;
            const unsigned short* gp = src + (rowBase + s * 8 + segRow) * (long)K
                                           + (long)kt * 64 + segColE;
            __builtin_amdgcn_global_load_lds((as1cv)gp,
                (as3v)(&lds[buf][slot][s * 512 + lane * 8]), 16, 0, 0);
        }
    };

    f32x4 acc[8][4];
    #pragma unroll
    for (int i = 0; i < 8; ++i)
        #pragma unroll
        for (int j = 0; j < 4; ++j)
            acc[i][j] = (f32x4){0.f, 0.f, 0.f, 0.f};

    bf16x8 bfrag[4][2];
    const int bRowBase = (wn & 1) * 64;
    const int NK = K >> 6;
    const int ITERS = K >> 7;

#define VM4   asm volatile("s_waitcnt vmcnt(4)" ::: "memory")
#define PHASE(BUF, Q, STAGES, VMW) do {                                              \
    bf16x8 af0_0, af0_1, af1_0, af1_1;                                               \
    { const unsigned short* Ah = &lds[BUF][wm][0];                                   \
      af0_0 = *(const bf16x8*)(Ah + ((Q)*32 + rr) * 64 + colSwz0);                   \
      af0_1 = *(const bf16x8*)(Ah + ((Q)*32 + rr) * 64 + colSwz1);                   \
      af1_0 = *(const bf16x8*)(Ah + ((Q)*32 + 16 + rr) * 64 + colSwz0);              \
      af1_1 = *(const bf16x8*)(Ah + ((Q)*32 + 16 + rr) * 64 + colSwz1); }            \
    if ((Q) == 0) { const unsigned short* Bh = &lds[BUF][2 + (wn >> 1)][0];          \
      _Pragma("unroll")                                                              \
      for (int nj = 0; nj < 4; ++nj) {                                               \
        bfrag[nj][0] = *(const bf16x8*)(Bh + (bRowBase + nj*16 + rr) * 64 + colSwz0);\
        bfrag[nj][1] = *(const bf16x8*)(Bh + (bRowBase + nj*16 + rr) * 64 + colSwz1);\
      } }                                                                            \
    STAGES;                                                                          \
    VMW;                                                                             \
    __builtin_amdgcn_s_barrier();                                                    \
    asm volatile("s_waitcnt lgkmcnt(0)" ::: "memory");                               \
    __builtin_amdgcn_sched_barrier(0);                                               \
    __builtin_amdgcn_s_setprio(1);                                                   \
    _Pragma("unroll")                                                                \
    for (int nj = 0; nj < 4; ++nj) {                                                 \
      acc[2*(Q)][nj]   = __builtin_amdgcn_mfma_f32_16x16x32_bf16(af0_0, bfrag[nj][0], acc[2*(Q)][nj],   0,0,0); \
      acc[2*(Q)][nj]   = __builtin_amdgcn_mfma_f32_16x16x32_bf16(af0_1, bfrag[nj][1], acc[2*(Q)][nj],   0,0,0); \
      acc[2*(Q)+1][nj] = __builtin_amdgcn_mfma_f32_16x16x32_bf16(af1_0, bfrag[nj][0], acc[2*(Q)+1][nj], 0,0,0); \
      acc[2*(Q)+1][nj] = __builtin_amdgcn_mfma_f32_16x16x32_bf16(af1_1, bfrag[nj][1], acc[2*(Q)+1][nj], 0,0,0); \
    }                                                                                \
    __builtin_amdgcn_s_setprio(0);                                                   \
    __builtin_amdgcn_s_barrier();                                                    \
} while (0)

    stage(0, 0, A,  m0,       0);
    stage(0, 1, A,  m0 + 128, 0);
    stage(0, 2, Bt, n0,       0);
    stage(0, 3, Bt, n0 + 128, 0);
    stage(1, 2, Bt, n0,       1);
    stage(1, 3, Bt, n0 + 128, 1);
    VM4;
    __builtin_amdgcn_s_barrier();

    for (int it = 0; it < ITERS; ++it) {
        const int kt1 = 2 * it + 1;
        int kt2 = 2 * it + 2; if (kt2 >= NK) kt2 = 0;
        int kt3 = 2 * it + 3; if (kt3 >= NK) kt3 = 1;

        PHASE(0, 0, stage(1, 0, A,  m0,       kt1), );
        PHASE(0, 1, stage(1, 1, A,  m0 + 128, kt1), );
        PHASE(0, 2, { stage(0, 2, Bt, n0, kt2); stage(0, 3, Bt, n0 + 128, kt2); }, );
        PHASE(0, 3, , VM4);
        PHASE(1, 0, stage(0, 0, A,  m0,       kt2), );
        PHASE(1, 1, stage(0, 1, A,  m0 + 128, kt2), );
        PHASE(1, 2, { stage(1, 2, Bt, n0, kt3); stage(1, 3, Bt, n0 + 128, kt3); }, );
        PHASE(1, 3, , VM4);
    }
#undef PHASE
#undef VM4

    #pragma unroll
    for (int mi = 0; mi < 8; ++mi) {
        const long rowb = m0 + wm * 128 + mi * 16 + cc * 4;
        #pragma unroll
        for (int nj = 0; nj < 4; ++nj) {
            const long col = n0 + wn * 64 + nj * 16 + rr;
            const float bv = bias[col];
            #pragma unroll
            for (int jj = 0; jj < 4; ++jj) {
                const float v = acc[mi][nj][jj] + bv;
                if (OUT_BF16) ((unsigned short*)C)[(rowb + jj) * N + col] = f2bf(v);
                else          ((float*)C)[(rowb + jj) * N + col] = v;
            }
        }
    }
}

// ---------- 4. column sums: total[b][d] = sum_t p[b,t,d] ----------
__global__ void k_colsum(const unsigned short* __restrict__ p, float* __restrict__ total, int T) {
    const int b = blockIdx.y;
    const int t0 = blockIdx.x * 64;
    const int tid = threadIdx.x;
    float s0 = 0.f, s1 = 0.f, s2 = 0.f, s3 = 0.f;
    const unsigned short* base = p + ((long)b * T + t0) * 1024 + tid * 4;
    for (int t = 0; t < 64; ++t) {
        ushort4 v = *(const ushort4*)(base + (long)t * 1024);
        s0 += bf2f(v.x); s1 += bf2f(v.y); s2 += bf2f(v.z); s3 += bf2f(v.w);
    }
    float* tp = total + b * 1024 + tid * 4;
    atomicAdd(tp + 0, s0); atomicAdd(tp + 1, s1);
    atomicAdd(tp + 2, s2); atomicAdd(tp + 3, s3);
}

// ---------- 5. FSMN v4: burst-load window + taps in regs, 32 outputs/thread ----------
// block: 64 d (lane) x 128 t (wave = 32-t chunk, 2 passes x 16). LDS: p-window
// staged row-major bf16 (vector b128 writes), taps staged fp32.
// Burst structure: 55 ds_read_u16 -> 640 unrolled FMA (16 indep chains), so
// even if regalloc sinks loads, cost stays LDS-class.
#define FS_ROWS 167   // 128 + 39
__global__ __launch_bounds__(256, 2) void k_fsmn(
    const unsigned short* __restrict__ p,   // (B*T, 1024) bf16
    const float* __restrict__ mw,           // (41, 1024) fp32
    const float* __restrict__ total,        // (B, 1024) fp32
    unsigned short* __restrict__ p2,        // (B*T, 1024) bf16
    int T)
{
    __shared__ unsigned short sp[FS_ROWS][64];   // [c][d], t = t0 + c - 39
    __shared__ float smw[41][64];
    const int b  = blockIdx.z;
    const int t0 = blockIdx.y * 128;
    const int d0 = blockIdx.x * 64;
    const int tid = threadIdx.x;

    // stage taps
    for (int idx = tid; idx < 41 * 64; idx += 256) {
        int r = idx >> 6, c = idx & 63;
        smw[r][c] = mw[r * 1024 + d0 + c];
    }
    // stage p window: 167 rows x 64 d, ushort8 per lane (8 lanes/row, 32 rows/iter)
    {
        const int row0 = tid >> 3;          // 0..31
        const int col8 = (tid & 7) * 8;     // 0,8,..,56
        #pragma unroll
        for (int i = 0; i < 6; ++i) {
            const int row = row0 + i * 32;
            if (row < FS_ROWS) {
                const int t = t0 + row - 39;
                u16x8 v = {0, 0, 0, 0, 0, 0, 0, 0};
                if (t >= 0)
                    v = *(const u16x8*)(p + ((long)b * T + t) * 1024 + d0 + col8);
                *(u16x8*)(&sp[row][col8]) = v;
            }
        }
    }
    __syncthreads();

    const int lane = tid & 63, wv = tid >> 6;
    const int d = d0 + lane;

    // taps -> registers (LDS source: remat-safe)
    float m[40];
    #pragma unroll
    for (int l = 0; l < 40; ++l) m[l] = smw[l + 1][lane];
    const float m0v = smw[0][lane];
    const float tot = total[b * 1024 + d];

    #pragma unroll
    for (int pass = 0; pass < 2; ++pass) {
        const int obase = wv * 32 + pass * 16;   // tile-t of first output
        // window w[j] = p[t0 + obase + j - 39] = sp[obase + j][lane], j=0..54
        float w[55];
        #pragma unroll
        for (int j = 0; j < 55; ++j) w[j] = bf2f(sp[obase + j][lane]);

        float acc[16];
        #pragma unroll
        for (int s = 0; s < 16; ++s) acc[s] = 0.f;
        #pragma unroll
        for (int lag = 0; lag < 40; ++lag) {
            const float mm = m[lag];
            #pragma unroll
            for (int s = 0; s < 16; ++s)
                acc[s] = fmaf(mm, w[s + 39 - lag], acc[s]);
        }

        float accw[16];
        {
            float S = 0.f;
            #pragma unroll
            for (int j = 0; j < 40; ++j) S += w[j];
            accw[0] = S;
            #pragma unroll
            for (int s = 1; s < 16; ++s) accw[s] = accw[s - 1] + w[s + 39] - w[s - 1];
        }

        unsigned short* ob = p2 + ((long)b * T + t0 + obase) * 1024 + d;
        #pragma unroll
        for (int s = 0; s < 16; ++s)
            ob[(long)s * 1024] = f2bf(acc[s] + m0v * (tot - accw[s]));
    }
}

// ---------- launch ----------
extern "C" void kernel_launch(void* const* d_in, const int* in_sizes, int n_in,
                              void* d_out, int out_size, void* d_ws, size_t ws_size,
                              hipStream_t stream) {
    const float* x  = (const float*)d_in[0];
    const float* W1 = (const float*)d_in[1];
    const float* b1 = (const float*)d_in[2];
    const float* W2 = (const float*)d_in[3];
    const float* b2 = (const float*)d_in[4];
    const float* mw = (const float*)d_in[5];
    float* out = (float*)d_out;

    const int B = 8, T = 2048;
    const long M = (long)B * T;          // 16384 rows
    const int N = 1024, K = 1024;

    char* ws = (char*)d_ws;
    unsigned short* x_bf   = (unsigned short*)(ws);
    unsigned short* W1t    = (unsigned short*)(ws + 33554432L);
    unsigned short* W2t    = (unsigned short*)(ws + 35651584L);
    unsigned short* p_bf   = (unsigned short*)(ws + 37748736L);
    float*          totals = (float*)(ws + 71303168L);
    unsigned short* p2_bf  = x_bf;

    k_cvt_bf16<<<2048, 256, 0, stream>>>(x, x_bf, M * 1024);

    dim3 tgrid(16, 16);
    k_transpose_bf16<<<tgrid, 256, 0, stream>>>(W1, W1t, K, N);
    k_transpose_bf16<<<tgrid, 256, 0, stream>>>(W2, W2t, K, N);

    k_gemm256<1><<<dim3((int)((M / 256) * (N / 256))), 512, 0, stream>>>(
        x_bf, W1t, b1, (void*)p_bf, (int)M, N, K);

    hipMemsetAsync(totals, 0, B * 1024 * sizeof(float), stream);
    k_colsum<<<dim3(T / 64, B), 256, 0, stream>>>(p_bf, totals, T);

    k_fsmn<<<dim3(1024 / 64, T / 128, B), 256, 0, stream>>>(p_bf, mw, totals, p2_bf, T);

    k_gemm256<0><<<dim3((int)((M / 256) * (N / 256))), 512, 0, stream>>>(
        p2_bf, W2t, b2, (void*)out, (int)M, N, K);
}

// Round 6
// 136.722 us; speedup vs baseline: 1.8402x; 1.0071x over previous
//
#include <hip/hip_runtime.h>

// ---------- small helpers ----------
typedef __attribute__((ext_vector_type(8))) short bf16x8;
typedef __attribute__((ext_vector_type(4))) float f32x4;
typedef __attribute__((ext_vector_type(8))) unsigned short u16x8;

typedef const __attribute__((address_space(1))) void* as1cv;
typedef __attribute__((address_space(3))) void* as3v;

__device__ __forceinline__ unsigned short f2bf(float f) {
    union { float f; unsigned u; } x; x.f = f;
    unsigned r = x.u + 0x7FFFu + ((x.u >> 16) & 1u);   // RNE
    return (unsigned short)(r >> 16);
}
__device__ __forceinline__ float bf2f(unsigned short u) {
    union { unsigned u; float f; } x; x.u = ((unsigned)u) << 16; return x.f;
}

// ---------- 1. fp32 -> bf16 convert (vectorized, grid-stride) ----------
__global__ void k_cvt_bf16(const float* __restrict__ in, unsigned short* __restrict__ out, long n) {
    long i = (long)blockIdx.x * blockDim.x + threadIdx.x;
    long stride = (long)gridDim.x * blockDim.x;
    long n4 = n >> 2;
    for (long j = i; j < n4; j += stride) {
        float4 v = ((const float4*)in)[j];
        ushort4 o;
        o.x = f2bf(v.x); o.y = f2bf(v.y); o.z = f2bf(v.z); o.w = f2bf(v.w);
        ((ushort4*)out)[j] = o;
    }
}

// ---------- 2. both weights (1024x1024 f32) -> transposed bf16, one launch ----------
__global__ void k_transpose_bf16(const float* __restrict__ W1, unsigned short* __restrict__ W1t,
                                 const float* __restrict__ W2, unsigned short* __restrict__ W2t) {
    const int rows = 1024, cols = 1024;
    const float* W = blockIdx.z ? W2 : W1;
    unsigned short* Wt = blockIdx.z ? W2t : W1t;
    __shared__ float tile[64][65];
    int r0 = blockIdx.y * 64, c0 = blockIdx.x * 64;
    #pragma unroll
    for (int i = 0; i < 16; ++i) {
        int idx = threadIdx.x + i * 256;
        int r = idx >> 6, c = idx & 63;
        tile[r][c] = W[(long)(r0 + r) * cols + (c0 + c)];
    }
    __syncthreads();
    #pragma unroll
    for (int i = 0; i < 16; ++i) {
        int idx = threadIdx.x + i * 256;
        int r = idx >> 6, c = idx & 63;
        Wt[(long)(c0 + r) * rows + (r0 + c)] = f2bf(tile[c][r]);
    }
}

// ---------- 3. GEMM 256x256 8-phase, BK=64, 8 waves; transposed-D epilogue ----------
// mfma(bfrag, afrag, acc) computes D = C^T fragments: D.col(lane&15)=C-row,
// D.row(cc*4+jj)=C-col -> each thread's 4 acc elems are 4 CONSECUTIVE C-cols
// of one row: packed 8B (bf16) / 16B (fp32) stores. Optional fused column-sum
// (bias included) for the FSMN 'total' term.
template<int OUT_BF16, int DO_COLSUM>
__global__ __launch_bounds__(512, 2) void k_gemm256(
    const unsigned short* __restrict__ A,
    const unsigned short* __restrict__ Bt,
    const float* __restrict__ bias,
    void* __restrict__ C,
    float* __restrict__ totals,
    int M, int N, int K)
{
    __shared__ unsigned short lds[2][4][8192];
    const int tid  = threadIdx.x;
    const int lane = tid & 63;
    const int w    = tid >> 6;          // wave 0..7
    const int wm   = w >> 2;            // 0..1 (M half)
    const int wn   = w & 3;             // 0..3 (N quarter)

    const int nwg = gridDim.x;
    const int cpx = nwg >> 3;
    const int wg  = (blockIdx.x & 7) * cpx + (blockIdx.x >> 3);
    const int nblks = N >> 8;
    const int mblk = wg / nblks, nblk = wg % nblks;
    const long m0 = (long)mblk << 8, n0 = (long)nblk << 8;

    const int segRow  = lane >> 3;
    const long segColE = (long)(((lane & 7) ^ segRow) << 3);

    const int rr = lane & 15, cc = lane >> 4;
    const int smask = (rr & 7) << 4;
    const int colSwz0 = (((cc * 16) ^ smask) >> 1);
    const int colSwz1 = (((64 + cc * 16) ^ smask) >> 1);

    auto stage = [&](int buf, int slot, const unsigned short* src, long rowBase, int kt) {
        #pragma unroll
        for (int g = 0; g < 2; ++g) {
            const int s = w + g * 8;
            const unsigned short* gp = src + (rowBase + s * 8 + segRow) * (long)K
                                           + (long)kt * 64 + segColE;
            __builtin_amdgcn_global_load_lds((as1cv)gp,
                (as3v)(&lds[buf][slot][s * 512 + lane * 8]), 16, 0, 0);
        }
    };

    // acc[nj][ri]: nj = C-col 16-group (wave's 64 cols), ri = C-row 16-group (128 rows)
    f32x4 acc[4][8];
    #pragma unroll
    for (int i = 0; i < 4; ++i)
        #pragma unroll
        for (int j = 0; j < 8; ++j)
            acc[i][j] = (f32x4){0.f, 0.f, 0.f, 0.f};

    bf16x8 bfrag[4][2];
    const int bRowBase = (wn & 1) * 64;
    const int NK = K >> 6;
    const int ITERS = K >> 7;

#define VM4   asm volatile("s_waitcnt vmcnt(4)" ::: "memory")
#define PHASE(BUF, Q, STAGES, VMW) do {                                              \
    bf16x8 af0_0, af0_1, af1_0, af1_1;                                               \
    { const unsigned short* Ah = &lds[BUF][wm][0];                                   \
      af0_0 = *(const bf16x8*)(Ah + ((Q)*32 + rr) * 64 + colSwz0);                   \
      af0_1 = *(const bf16x8*)(Ah + ((Q)*32 + rr) * 64 + colSwz1);                   \
      af1_0 = *(const bf16x8*)(Ah + ((Q)*32 + 16 + rr) * 64 + colSwz0);              \
      af1_1 = *(const bf16x8*)(Ah + ((Q)*32 + 16 + rr) * 64 + colSwz1); }            \
    if ((Q) == 0) { const unsigned short* Bh = &lds[BUF][2 + (wn >> 1)][0];          \
      _Pragma("unroll")                                                              \
      for (int nj = 0; nj < 4; ++nj) {                                               \
        bfrag[nj][0] = *(const bf16x8*)(Bh + (bRowBase + nj*16 + rr) * 64 + colSwz0);\
        bfrag[nj][1] = *(const bf16x8*)(Bh + (bRowBase + nj*16 + rr) * 64 + colSwz1);\
      } }                                                                            \
    STAGES;                                                                          \
    VMW;                                                                             \
    __builtin_amdgcn_s_barrier();                                                    \
    asm volatile("s_waitcnt lgkmcnt(0)" ::: "memory");                               \
    __builtin_amdgcn_sched_barrier(0);                                               \
    __builtin_amdgcn_s_setprio(1);                                                   \
    _Pragma("unroll")                                                                \
    for (int nj = 0; nj < 4; ++nj) {                                                 \
      acc[nj][2*(Q)]   = __builtin_amdgcn_mfma_f32_16x16x32_bf16(bfrag[nj][0], af0_0, acc[nj][2*(Q)],   0,0,0); \
      acc[nj][2*(Q)]   = __builtin_amdgcn_mfma_f32_16x16x32_bf16(bfrag[nj][1], af0_1, acc[nj][2*(Q)],   0,0,0); \
      acc[nj][2*(Q)+1] = __builtin_amdgcn_mfma_f32_16x16x32_bf16(bfrag[nj][0], af1_0, acc[nj][2*(Q)+1], 0,0,0); \
      acc[nj][2*(Q)+1] = __builtin_amdgcn_mfma_f32_16x16x32_bf16(bfrag[nj][1], af1_1, acc[nj][2*(Q)+1], 0,0,0); \
    }                                                                                \
    __builtin_amdgcn_s_setprio(0);                                                   \
    __builtin_amdgcn_s_barrier();                                                    \
} while (0)

    stage(0, 0, A,  m0,       0);
    stage(0, 1, A,  m0 + 128, 0);
    stage(0, 2, Bt, n0,       0);
    stage(0, 3, Bt, n0 + 128, 0);
    stage(1, 2, Bt, n0,       1);
    stage(1, 3, Bt, n0 + 128, 1);
    VM4;
    __builtin_amdgcn_s_barrier();

    for (int it = 0; it < ITERS; ++it) {
        const int kt1 = 2 * it + 1;
        int kt2 = 2 * it + 2; if (kt2 >= NK) kt2 = 0;
        int kt3 = 2 * it + 3; if (kt3 >= NK) kt3 = 1;

        PHASE(0, 0, stage(1, 0, A,  m0,       kt1), );
        PHASE(0, 1, stage(1, 1, A,  m0 + 128, kt1), );
        PHASE(0, 2, { stage(0, 2, Bt, n0, kt2); stage(0, 3, Bt, n0 + 128, kt2); }, );
        PHASE(0, 3, , VM4);
        PHASE(1, 0, stage(0, 0, A,  m0,       kt2), );
        PHASE(1, 1, stage(0, 1, A,  m0 + 128, kt2), );
        PHASE(1, 2, { stage(1, 2, Bt, n0, kt3); stage(1, 3, Bt, n0 + 128, kt3); }, );
        PHASE(1, 3, , VM4);
    }
#undef PHASE
#undef VM4

    // epilogue: thread owns rows (wm*128 + ri*16 + rr), cols (wn*64 + nj*16 + cc*4 .. +3)
    #pragma unroll
    for (int nj = 0; nj < 4; ++nj) {
        const long colb = n0 + wn * 64 + nj * 16 + cc * 4;
        const float4 bv4 = *(const float4*)(bias + colb);
        float cs0 = 0.f, cs1 = 0.f, cs2 = 0.f, cs3 = 0.f;
        #pragma unroll
        for (int ri = 0; ri < 8; ++ri) {
            const long row = m0 + wm * 128 + ri * 16 + rr;
            const f32x4 v = acc[nj][ri];
            const float o0 = v[0] + bv4.x, o1 = v[1] + bv4.y;
            const float o2 = v[2] + bv4.z, o3 = v[3] + bv4.w;
            if (DO_COLSUM) { cs0 += o0; cs1 += o1; cs2 += o2; cs3 += o3; }
            if (OUT_BF16) {
                uint2 pk;
                pk.x = ((unsigned)f2bf(o1) << 16) | f2bf(o0);
                pk.y = ((unsigned)f2bf(o3) << 16) | f2bf(o2);
                *(uint2*)((unsigned short*)C + row * N + colb) = pk;
            } else {
                float4 pk = {o0, o1, o2, o3};
                *(float4*)((float*)C + row * N + colb) = pk;
            }
        }
        if (DO_COLSUM) {
            #pragma unroll
            for (int s = 1; s < 16; s <<= 1) {
                cs0 += __shfl_xor(cs0, s, 64);
                cs1 += __shfl_xor(cs1, s, 64);
                cs2 += __shfl_xor(cs2, s, 64);
                cs3 += __shfl_xor(cs3, s, 64);
            }
            if (rr == 0) {
                const int b = (int)(m0 >> 11);      // 2048 rows per batch
                float* tp = totals + b * 1024 + colb;
                atomicAdd(tp + 0, cs0); atomicAdd(tp + 1, cs1);
                atomicAdd(tp + 2, cs2); atomicAdd(tp + 3, cs3);
            }
        }
    }
}

// ---------- 4. FSMN v4: burst-load window + taps in regs, 32 outputs/thread ----------
#define FS_ROWS 167   // 128 + 39
__global__ __launch_bounds__(256, 2) void k_fsmn(
    const unsigned short* __restrict__ p,   // (B*T, 1024) bf16
    const float* __restrict__ mw,           // (41, 1024) fp32
    const float* __restrict__ total,        // (B, 1024) fp32
    unsigned short* __restrict__ p2,        // (B*T, 1024) bf16
    int T)
{
    __shared__ unsigned short sp[FS_ROWS][64];   // [c][d], t = t0 + c - 39
    __shared__ float smw[41][64];
    const int b  = blockIdx.z;
    const int t0 = blockIdx.y * 128;
    const int d0 = blockIdx.x * 64;
    const int tid = threadIdx.x;

    for (int idx = tid; idx < 41 * 64; idx += 256) {
        int r = idx >> 6, c = idx & 63;
        smw[r][c] = mw[r * 1024 + d0 + c];
    }
    {
        const int row0 = tid >> 3;
        const int col8 = (tid & 7) * 8;
        #pragma unroll
        for (int i = 0; i < 6; ++i) {
            const int row = row0 + i * 32;
            if (row < FS_ROWS) {
                const int t = t0 + row - 39;
                u16x8 v = {0, 0, 0, 0, 0, 0, 0, 0};
                if (t >= 0)
                    v = *(const u16x8*)(p + ((long)b * T + t) * 1024 + d0 + col8);
                *(u16x8*)(&sp[row][col8]) = v;
            }
        }
    }
    __syncthreads();

    const int lane = tid & 63, wv = tid >> 6;
    const int d = d0 + lane;

    float m[40];
    #pragma unroll
    for (int l = 0; l < 40; ++l) m[l] = smw[l + 1][lane];
    const float m0v = smw[0][lane];
    const float tot = total[b * 1024 + d];

    #pragma unroll
    for (int pass = 0; pass < 2; ++pass) {
        const int obase = wv * 32 + pass * 16;
        float w[55];
        #pragma unroll
        for (int j = 0; j < 55; ++j) w[j] = bf2f(sp[obase + j][lane]);

        float acc[16];
        #pragma unroll
        for (int s = 0; s < 16; ++s) acc[s] = 0.f;
        #pragma unroll
        for (int lag = 0; lag < 40; ++lag) {
            const float mm = m[lag];
            #pragma unroll
            for (int s = 0; s < 16; ++s)
                acc[s] = fmaf(mm, w[s + 39 - lag], acc[s]);
        }

        float accw[16];
        {
            float S = 0.f;
            #pragma unroll
            for (int j = 0; j < 40; ++j) S += w[j];
            accw[0] = S;
            #pragma unroll
            for (int s = 1; s < 16; ++s) accw[s] = accw[s - 1] + w[s + 39] - w[s - 1];
        }

        unsigned short* ob = p2 + ((long)b * T + t0 + obase) * 1024 + d;
        #pragma unroll
        for (int s = 0; s < 16; ++s)
            ob[(long)s * 1024] = f2bf(acc[s] + m0v * (tot - accw[s]));
    }
}

// ---------- launch ----------
extern "C" void kernel_launch(void* const* d_in, const int* in_sizes, int n_in,
                              void* d_out, int out_size, void* d_ws, size_t ws_size,
                              hipStream_t stream) {
    const float* x  = (const float*)d_in[0];
    const float* W1 = (const float*)d_in[1];
    const float* b1 = (const float*)d_in[2];
    const float* W2 = (const float*)d_in[3];
    const float* b2 = (const float*)d_in[4];
    const float* mw = (const float*)d_in[5];
    float* out = (float*)d_out;

    const int B = 8, T = 2048;
    const long M = (long)B * T;          // 16384 rows
    const int N = 1024, K = 1024;

    char* ws = (char*)d_ws;
    unsigned short* x_bf   = (unsigned short*)(ws);
    unsigned short* W1t    = (unsigned short*)(ws + 33554432L);
    unsigned short* W2t    = (unsigned short*)(ws + 35651584L);
    unsigned short* p_bf   = (unsigned short*)(ws + 37748736L);
    float*          totals = (float*)(ws + 71303168L);
    unsigned short* p2_bf  = x_bf;

    k_cvt_bf16<<<2048, 256, 0, stream>>>(x, x_bf, M * 1024);

    k_transpose_bf16<<<dim3(16, 16, 2), 256, 0, stream>>>(W1, W1t, W2, W2t);

    hipMemsetAsync(totals, 0, B * 1024 * sizeof(float), stream);

    k_gemm256<1, 1><<<dim3((int)((M / 256) * (N / 256))), 512, 0, stream>>>(
        x_bf, W1t, b1, (void*)p_bf, totals, (int)M, N, K);

    k_fsmn<<<dim3(1024 / 64, T / 128, B), 256, 0, stream>>>(p_bf, mw, totals, p2_bf, T);

    k_gemm256<0, 0><<<dim3((int)((M / 256) * (N / 256))), 512, 0, stream>>>(
        p2_bf, W2t, b2, (void*)out, nullptr, (int)M, N, K);
}

// Round 7
// 136.211 us; speedup vs baseline: 1.8471x; 1.0038x over previous
//
#include <hip/hip_runtime.h>

// ---------- small helpers ----------
typedef __attribute__((ext_vector_type(8))) short bf16x8;
typedef __attribute__((ext_vector_type(4))) float f32x4;
typedef __attribute__((ext_vector_type(8))) unsigned short u16x8;

typedef const __attribute__((address_space(1))) void* as1cv;
typedef __attribute__((address_space(3))) void* as3v;

__device__ __forceinline__ unsigned short f2bf(float f) {
    union { float f; unsigned u; } x; x.f = f;
    unsigned r = x.u + 0x7FFFu + ((x.u >> 16) & 1u);   // RNE
    return (unsigned short)(r >> 16);
}
__device__ __forceinline__ float bf2f(unsigned short u) {
    union { unsigned u; float f; } x; x.u = ((unsigned)u) << 16; return x.f;
}

// ---------- 1. fp32 -> bf16 convert (vectorized, grid-stride) ----------
__global__ void k_cvt_bf16(const float* __restrict__ in, unsigned short* __restrict__ out, long n) {
    long i = (long)blockIdx.x * blockDim.x + threadIdx.x;
    long stride = (long)gridDim.x * blockDim.x;
    long n4 = n >> 2;
    for (long j = i; j < n4; j += stride) {
        float4 v = ((const float4*)in)[j];
        ushort4 o;
        o.x = f2bf(v.x); o.y = f2bf(v.y); o.z = f2bf(v.z); o.w = f2bf(v.w);
        ((ushort4*)out)[j] = o;
    }
}

// ---------- 2. both weights (1024x1024 f32) -> transposed bf16, one launch ----------
__global__ void k_transpose_bf16(const float* __restrict__ W1, unsigned short* __restrict__ W1t,
                                 const float* __restrict__ W2, unsigned short* __restrict__ W2t) {
    const int rows = 1024, cols = 1024;
    const float* W = blockIdx.z ? W2 : W1;
    unsigned short* Wt = blockIdx.z ? W2t : W1t;
    __shared__ float tile[64][65];
    int r0 = blockIdx.y * 64, c0 = blockIdx.x * 64;
    #pragma unroll
    for (int i = 0; i < 16; ++i) {
        int idx = threadIdx.x + i * 256;
        int r = idx >> 6, c = idx & 63;
        tile[r][c] = W[(long)(r0 + r) * cols + (c0 + c)];
    }
    __syncthreads();
    #pragma unroll
    for (int i = 0; i < 16; ++i) {
        int idx = threadIdx.x + i * 256;
        int r = idx >> 6, c = idx & 63;
        Wt[(long)(c0 + r) * rows + (r0 + c)] = f2bf(tile[c][r]);
    }
}

// ---------- 3. GEMM 256x256 8-phase (R5 layout), BK=64, 8 waves ----------
// R5-proven epilogue layout (un-swapped operands). MFMA order k-outer so
// same-accumulator reuse is 8 MFMAs apart (no dependent back-to-back pairs).
// Fused column-sum (bias included) for the FSMN 'total' term.
template<int OUT_BF16, int DO_COLSUM>
__global__ __launch_bounds__(512, 2) void k_gemm256(
    const unsigned short* __restrict__ A,
    const unsigned short* __restrict__ Bt,
    const float* __restrict__ bias,
    void* __restrict__ C,
    float* __restrict__ totals,
    int M, int N, int K)
{
    __shared__ unsigned short lds[2][4][8192];
    const int tid  = threadIdx.x;
    const int lane = tid & 63;
    const int w    = tid >> 6;          // wave 0..7
    const int wm   = w >> 2;            // 0..1 (M half)
    const int wn   = w & 3;             // 0..3 (N quarter)

    const int nwg = gridDim.x;
    const int cpx = nwg >> 3;
    const int wg  = (blockIdx.x & 7) * cpx + (blockIdx.x >> 3);
    const int nblks = N >> 8;
    const int mblk = wg / nblks, nblk = wg % nblks;
    const long m0 = (long)mblk << 8, n0 = (long)nblk << 8;

    const int segRow  = lane >> 3;
    const long segColE = (long)(((lane & 7) ^ segRow) << 3);

    const int rr = lane & 15, cc = lane >> 4;
    const int smask = (rr & 7) << 4;
    const int colSwz0 = (((cc * 16) ^ smask) >> 1);
    const int colSwz1 = (((64 + cc * 16) ^ smask) >> 1);

    auto stage = [&](int buf, int slot, const unsigned short* src, long rowBase, int kt) {
        #pragma unroll
        for (int g = 0; g < 2; ++g) {
            const int s = w + g * 8;
            const unsigned short* gp = src + (rowBase + s * 8 + segRow) * (long)K
                                           + (long)kt * 64 + segColE;
            __builtin_amdgcn_global_load_lds((as1cv)gp,
                (as3v)(&lds[buf][slot][s * 512 + lane * 8]), 16, 0, 0);
        }
    };

    // acc[mi][nj]: mi = row 16-group (wave's 128 rows), nj = col 16-group (64 cols)
    f32x4 acc[8][4];
    #pragma unroll
    for (int i = 0; i < 8; ++i)
        #pragma unroll
        for (int j = 0; j < 4; ++j)
            acc[i][j] = (f32x4){0.f, 0.f, 0.f, 0.f};

    bf16x8 bfrag[4][2];
    const int bRowBase = (wn & 1) * 64;
    const int NK = K >> 6;
    const int ITERS = K >> 7;

#define VM4   asm volatile("s_waitcnt vmcnt(4)" ::: "memory")
#define PHASE(BUF, Q, STAGES, VMW) do {                                              \
    bf16x8 af0[2], af1[2];                                                           \
    { const unsigned short* Ah = &lds[BUF][wm][0];                                   \
      af0[0] = *(const bf16x8*)(Ah + ((Q)*32 + rr) * 64 + colSwz0);                  \
      af0[1] = *(const bf16x8*)(Ah + ((Q)*32 + rr) * 64 + colSwz1);                  \
      af1[0] = *(const bf16x8*)(Ah + ((Q)*32 + 16 + rr) * 64 + colSwz0);             \
      af1[1] = *(const bf16x8*)(Ah + ((Q)*32 + 16 + rr) * 64 + colSwz1); }           \
    if ((Q) == 0) { const unsigned short* Bh = &lds[BUF][2 + (wn >> 1)][0];          \
      _Pragma("unroll")                                                              \
      for (int nj = 0; nj < 4; ++nj) {                                               \
        bfrag[nj][0] = *(const bf16x8*)(Bh + (bRowBase + nj*16 + rr) * 64 + colSwz0);\
        bfrag[nj][1] = *(const bf16x8*)(Bh + (bRowBase + nj*16 + rr) * 64 + colSwz1);\
      } }                                                                            \
    STAGES;                                                                          \
    VMW;                                                                             \
    __builtin_amdgcn_s_barrier();                                                    \
    asm volatile("s_waitcnt lgkmcnt(0)" ::: "memory");                               \
    __builtin_amdgcn_sched_barrier(0);                                               \
    __builtin_amdgcn_s_setprio(1);                                                   \
    _Pragma("unroll")                                                                \
    for (int k = 0; k < 2; ++k)                                                      \
      _Pragma("unroll")                                                              \
      for (int nj = 0; nj < 4; ++nj) {                                               \
        acc[2*(Q)][nj]   = __builtin_amdgcn_mfma_f32_16x16x32_bf16(af0[k], bfrag[nj][k], acc[2*(Q)][nj],   0,0,0); \
        acc[2*(Q)+1][nj] = __builtin_amdgcn_mfma_f32_16x16x32_bf16(af1[k], bfrag[nj][k], acc[2*(Q)+1][nj], 0,0,0); \
      }                                                                              \
    __builtin_amdgcn_s_setprio(0);                                                   \
    __builtin_amdgcn_s_barrier();                                                    \
} while (0)

    stage(0, 0, A,  m0,       0);
    stage(0, 1, A,  m0 + 128, 0);
    stage(0, 2, Bt, n0,       0);
    stage(0, 3, Bt, n0 + 128, 0);
    stage(1, 2, Bt, n0,       1);
    stage(1, 3, Bt, n0 + 128, 1);
    VM4;
    __builtin_amdgcn_s_barrier();

    for (int it = 0; it < ITERS; ++it) {
        const int kt1 = 2 * it + 1;
        int kt2 = 2 * it + 2; if (kt2 >= NK) kt2 = 0;
        int kt3 = 2 * it + 3; if (kt3 >= NK) kt3 = 1;

        PHASE(0, 0, stage(1, 0, A,  m0,       kt1), );
        PHASE(0, 1, stage(1, 1, A,  m0 + 128, kt1), );
        PHASE(0, 2, { stage(0, 2, Bt, n0, kt2); stage(0, 3, Bt, n0 + 128, kt2); }, );
        PHASE(0, 3, , VM4);
        PHASE(1, 0, stage(0, 0, A,  m0,       kt2), );
        PHASE(1, 1, stage(0, 1, A,  m0 + 128, kt2), );
        PHASE(1, 2, { stage(1, 2, Bt, n0, kt3); stage(1, 3, Bt, n0 + 128, kt3); }, );
        PHASE(1, 3, , VM4);
    }
#undef PHASE
#undef VM4

    // epilogue (R5 layout): C/D col = rr, row = cc*4 + jj within 16x16 frag
    const long rowb0 = m0 + wm * 128 + cc * 4;
    #pragma unroll
    for (int nj = 0; nj < 4; ++nj) {
        const long col = n0 + wn * 64 + nj * 16 + rr;
        const float bv = bias[col];
        float cs = 0.f;
        #pragma unroll
        for (int mi = 0; mi < 8; ++mi) {
            const long rowb = rowb0 + mi * 16;
            #pragma unroll
            for (int jj = 0; jj < 4; ++jj) {
                const float v = acc[mi][nj][jj] + bv;
                if (DO_COLSUM) cs += v;
                if (OUT_BF16) ((unsigned short*)C)[(rowb + jj) * N + col] = f2bf(v);
                else          ((float*)C)[(rowb + jj) * N + col] = v;
            }
        }
        if (DO_COLSUM) {
            // 4 lanes (cc=0..3) share this col; combine then one atomic
            cs += __shfl_xor(cs, 16, 64);
            cs += __shfl_xor(cs, 32, 64);
            if (cc == 0) {
                const int b = (int)(m0 >> 11);      // 2048 rows per batch
                atomicAdd(totals + b * 1024 + col, cs);
            }
        }
    }
}

// ---------- 4. FSMN v4: burst-load window + taps in regs, 32 outputs/thread ----------
#define FS_ROWS 167   // 128 + 39
__global__ __launch_bounds__(256, 2) void k_fsmn(
    const unsigned short* __restrict__ p,   // (B*T, 1024) bf16
    const float* __restrict__ mw,           // (41, 1024) fp32
    const float* __restrict__ total,        // (B, 1024) fp32
    unsigned short* __restrict__ p2,        // (B*T, 1024) bf16
    int T)
{
    __shared__ unsigned short sp[FS_ROWS][64];   // [c][d], t = t0 + c - 39
    __shared__ float smw[41][64];
    const int b  = blockIdx.z;
    const int t0 = blockIdx.y * 128;
    const int d0 = blockIdx.x * 64;
    const int tid = threadIdx.x;

    for (int idx = tid; idx < 41 * 64; idx += 256) {
        int r = idx >> 6, c = idx & 63;
        smw[r][c] = mw[r * 1024 + d0 + c];
    }
    {
        const int row0 = tid >> 3;
        const int col8 = (tid & 7) * 8;
        #pragma unroll
        for (int i = 0; i < 6; ++i) {
            const int row = row0 + i * 32;
            if (row < FS_ROWS) {
                const int t = t0 + row - 39;
                u16x8 v = {0, 0, 0, 0, 0, 0, 0, 0};
                if (t >= 0)
                    v = *(const u16x8*)(p + ((long)b * T + t) * 1024 + d0 + col8);
                *(u16x8*)(&sp[row][col8]) = v;
            }
        }
    }
    __syncthreads();

    const int lane = tid & 63, wv = tid >> 6;
    const int d = d0 + lane;

    float m[40];
    #pragma unroll
    for (int l = 0; l < 40; ++l) m[l] = smw[l + 1][lane];
    const float m0v = smw[0][lane];
    const float tot = total[b * 1024 + d];

    #pragma unroll
    for (int pass = 0; pass < 2; ++pass) {
        const int obase = wv * 32 + pass * 16;
        float w[55];
        #pragma unroll
        for (int j = 0; j < 55; ++j) w[j] = bf2f(sp[obase + j][lane]);

        float acc[16];
        #pragma unroll
        for (int s = 0; s < 16; ++s) acc[s] = 0.f;
        #pragma unroll
        for (int lag = 0; lag < 40; ++lag) {
            const float mm = m[lag];
            #pragma unroll
            for (int s = 0; s < 16; ++s)
                acc[s] = fmaf(mm, w[s + 39 - lag], acc[s]);
        }

        float accw[16];
        {
            float S = 0.f;
            #pragma unroll
            for (int j = 0; j < 40; ++j) S += w[j];
            accw[0] = S;
            #pragma unroll
            for (int s = 1; s < 16; ++s) accw[s] = accw[s - 1] + w[s + 39] - w[s - 1];
        }

        unsigned short* ob = p2 + ((long)b * T + t0 + obase) * 1024 + d;
        #pragma unroll
        for (int s = 0; s < 16; ++s)
            ob[(long)s * 1024] = f2bf(acc[s] + m0v * (tot - accw[s]));
    }
}

// ---------- launch ----------
extern "C" void kernel_launch(void* const* d_in, const int* in_sizes, int n_in,
                              void* d_out, int out_size, void* d_ws, size_t ws_size,
                              hipStream_t stream) {
    const float* x  = (const float*)d_in[0];
    const float* W1 = (const float*)d_in[1];
    const float* b1 = (const float*)d_in[2];
    const float* W2 = (const float*)d_in[3];
    const float* b2 = (const float*)d_in[4];
    const float* mw = (const float*)d_in[5];
    float* out = (float*)d_out;

    const int B = 8, T = 2048;
    const long M = (long)B * T;          // 16384 rows
    const int N = 1024, K = 1024;

    char* ws = (char*)d_ws;
    unsigned short* x_bf   = (unsigned short*)(ws);
    unsigned short* W1t    = (unsigned short*)(ws + 33554432L);
    unsigned short* W2t    = (unsigned short*)(ws + 35651584L);
    unsigned short* p_bf   = (unsigned short*)(ws + 37748736L);
    float*          totals = (float*)(ws + 71303168L);
    unsigned short* p2_bf  = x_bf;

    k_cvt_bf16<<<2048, 256, 0, stream>>>(x, x_bf, M * 1024);

    k_transpose_bf16<<<dim3(16, 16, 2), 256, 0, stream>>>(W1, W1t, W2, W2t);

    hipMemsetAsync(totals, 0, B * 1024 * sizeof(float), stream);

    k_gemm256<1, 1><<<dim3((int)((M / 256) * (N / 256))), 512, 0, stream>>>(
        x_bf, W1t, b1, (void*)p_bf, totals, (int)M, N, K);

    k_fsmn<<<dim3(1024 / 64, T / 128, B), 256, 0, stream>>>(p_bf, mw, totals, p2_bf, T);

    k_gemm256<0, 0><<<dim3((int)((M / 256) * (N / 256))), 512, 0, stream>>>(
        p2_bf, W2t, b2, (void*)out, nullptr, (int)M, N, K);
}

// Round 8
// 127.850 us; speedup vs baseline: 1.9679x; 1.0654x over previous
//
#include <hip/hip_runtime.h>

// ---------- small helpers ----------
typedef __attribute__((ext_vector_type(8))) short bf16x8;
typedef __attribute__((ext_vector_type(4))) float f32x4;
typedef __attribute__((ext_vector_type(8))) unsigned short u16x8;

typedef const __attribute__((address_space(1))) void* as1cv;
typedef __attribute__((address_space(3))) void* as3v;

__device__ __forceinline__ unsigned short f2bf(float f) {
    union { float f; unsigned u; } x; x.f = f;
    unsigned r = x.u + 0x7FFFu + ((x.u >> 16) & 1u);   // RNE
    return (unsigned short)(r >> 16);
}
__device__ __forceinline__ float bf2f(unsigned short u) {
    union { unsigned u; float f; } x; x.u = ((unsigned)u) << 16; return x.f;
}

// ---------- 1. fp32 -> bf16 convert (vectorized, grid-stride) ----------
__global__ void k_cvt_bf16(const float* __restrict__ in, unsigned short* __restrict__ out, long n) {
    long i = (long)blockIdx.x * blockDim.x + threadIdx.x;
    long stride = (long)gridDim.x * blockDim.x;
    long n4 = n >> 2;
    for (long j = i; j < n4; j += stride) {
        float4 v = ((const float4*)in)[j];
        ushort4 o;
        o.x = f2bf(v.x); o.y = f2bf(v.y); o.z = f2bf(v.z); o.w = f2bf(v.w);
        ((ushort4*)out)[j] = o;
    }
}

// ---------- 2. both weights (1024x1024 f32) -> transposed bf16, one launch ----------
__global__ void k_transpose_bf16(const float* __restrict__ W1, unsigned short* __restrict__ W1t,
                                 const float* __restrict__ W2, unsigned short* __restrict__ W2t) {
    const int rows = 1024, cols = 1024;
    const float* W = blockIdx.z ? W2 : W1;
    unsigned short* Wt = blockIdx.z ? W2t : W1t;
    __shared__ float tile[64][65];
    int r0 = blockIdx.y * 64, c0 = blockIdx.x * 64;
    #pragma unroll
    for (int i = 0; i < 16; ++i) {
        int idx = threadIdx.x + i * 256;
        int r = idx >> 6, c = idx & 63;
        tile[r][c] = W[(long)(r0 + r) * cols + (c0 + c)];
    }
    __syncthreads();
    #pragma unroll
    for (int i = 0; i < 16; ++i) {
        int idx = threadIdx.x + i * 256;
        int r = idx >> 6, c = idx & 63;
        Wt[(long)(c0 + r) * rows + (r0 + c)] = f2bf(tile[c][r]);
    }
}

// ---------- 3. GEMM 256x256 8-phase — EXACT R4 structure (proven 43us) ----------
// R4 PHASE body + R4 mi-outer epilogue (store order matters: tight per-row
// runs keep 128B sectors closed fast; nj-outer order cost +10MB WRITE_SIZE
// and +5us). Colsum fused as cs[4] accumulated inside the same loops.
template<int OUT_BF16, int DO_COLSUM>
__global__ __launch_bounds__(512, 2) void k_gemm256(
    const unsigned short* __restrict__ A,
    const unsigned short* __restrict__ Bt,
    const float* __restrict__ bias,
    void* __restrict__ C,
    float* __restrict__ totals,
    int M, int N, int K)
{
    __shared__ unsigned short lds[2][4][8192];
    const int tid  = threadIdx.x;
    const int lane = tid & 63;
    const int w    = tid >> 6;          // wave 0..7
    const int wm   = w >> 2;            // 0..1 (M half)
    const int wn   = w & 3;             // 0..3 (N quarter)

    const int nwg = gridDim.x;
    const int cpx = nwg >> 3;
    const int wg  = (blockIdx.x & 7) * cpx + (blockIdx.x >> 3);
    const int nblks = N >> 8;
    const int mblk = wg / nblks, nblk = wg % nblks;
    const long m0 = (long)mblk << 8, n0 = (long)nblk << 8;

    const int segRow  = lane >> 3;
    const long segColE = (long)(((lane & 7) ^ segRow) << 3);

    const int rr = lane & 15, cc = lane >> 4;
    const int smask = (rr & 7) << 4;
    const int colSwz0 = (((cc * 16) ^ smask) >> 1);
    const int colSwz1 = (((64 + cc * 16) ^ smask) >> 1);

    auto stage = [&](int buf, int slot, const unsigned short* src, long rowBase, int kt) {
        #pragma unroll
        for (int g = 0; g < 2; ++g) {
            const int s = w + g * 8;
            const unsigned short* gp = src + (rowBase + s * 8 + segRow) * (long)K
                                           + (long)kt * 64 + segColE;
            __builtin_amdgcn_global_load_lds((as1cv)gp,
                (as3v)(&lds[buf][slot][s * 512 + lane * 8]), 16, 0, 0);
        }
    };

    // acc[mi][nj]: mi = row 16-group (wave's 128 rows), nj = col 16-group (64 cols)
    f32x4 acc[8][4];
    #pragma unroll
    for (int i = 0; i < 8; ++i)
        #pragma unroll
        for (int j = 0; j < 4; ++j)
            acc[i][j] = (f32x4){0.f, 0.f, 0.f, 0.f};

    bf16x8 bfrag[4][2];
    const int bRowBase = (wn & 1) * 64;
    const int NK = K >> 6;
    const int ITERS = K >> 7;

#define VM4   asm volatile("s_waitcnt vmcnt(4)" ::: "memory")
#define PHASE(BUF, Q, STAGES, VMW) do {                                              \
    bf16x8 af0_0, af0_1, af1_0, af1_1;                                               \
    { const unsigned short* Ah = &lds[BUF][wm][0];                                   \
      af0_0 = *(const bf16x8*)(Ah + ((Q)*32 + rr) * 64 + colSwz0);                   \
      af0_1 = *(const bf16x8*)(Ah + ((Q)*32 + rr) * 64 + colSwz1);                   \
      af1_0 = *(const bf16x8*)(Ah + ((Q)*32 + 16 + rr) * 64 + colSwz0);              \
      af1_1 = *(const bf16x8*)(Ah + ((Q)*32 + 16 + rr) * 64 + colSwz1); }            \
    if ((Q) == 0) { const unsigned short* Bh = &lds[BUF][2 + (wn >> 1)][0];          \
      _Pragma("unroll")                                                              \
      for (int nj = 0; nj < 4; ++nj) {                                               \
        bfrag[nj][0] = *(const bf16x8*)(Bh + (bRowBase + nj*16 + rr) * 64 + colSwz0);\
        bfrag[nj][1] = *(const bf16x8*)(Bh + (bRowBase + nj*16 + rr) * 64 + colSwz1);\
      } }                                                                            \
    STAGES;                                                                          \
    VMW;                                                                             \
    __builtin_amdgcn_s_barrier();                                                    \
    asm volatile("s_waitcnt lgkmcnt(0)" ::: "memory");                               \
    __builtin_amdgcn_sched_barrier(0);                                               \
    __builtin_amdgcn_s_setprio(1);                                                   \
    _Pragma("unroll")                                                                \
    for (int nj = 0; nj < 4; ++nj) {                                                 \
      acc[2*(Q)][nj]   = __builtin_amdgcn_mfma_f32_16x16x32_bf16(af0_0, bfrag[nj][0], acc[2*(Q)][nj],   0,0,0); \
      acc[2*(Q)][nj]   = __builtin_amdgcn_mfma_f32_16x16x32_bf16(af0_1, bfrag[nj][1], acc[2*(Q)][nj],   0,0,0); \
      acc[2*(Q)+1][nj] = __builtin_amdgcn_mfma_f32_16x16x32_bf16(af1_0, bfrag[nj][0], acc[2*(Q)+1][nj], 0,0,0); \
      acc[2*(Q)+1][nj] = __builtin_amdgcn_mfma_f32_16x16x32_bf16(af1_1, bfrag[nj][1], acc[2*(Q)+1][nj], 0,0,0); \
    }                                                                                \
    __builtin_amdgcn_s_setprio(0);                                                   \
    __builtin_amdgcn_s_barrier();                                                    \
} while (0)

    stage(0, 0, A,  m0,       0);
    stage(0, 1, A,  m0 + 128, 0);
    stage(0, 2, Bt, n0,       0);
    stage(0, 3, Bt, n0 + 128, 0);
    stage(1, 2, Bt, n0,       1);
    stage(1, 3, Bt, n0 + 128, 1);
    VM4;
    __builtin_amdgcn_s_barrier();

    for (int it = 0; it < ITERS; ++it) {
        const int kt1 = 2 * it + 1;
        int kt2 = 2 * it + 2; if (kt2 >= NK) kt2 = 0;
        int kt3 = 2 * it + 3; if (kt3 >= NK) kt3 = 1;

        PHASE(0, 0, stage(1, 0, A,  m0,       kt1), );
        PHASE(0, 1, stage(1, 1, A,  m0 + 128, kt1), );
        PHASE(0, 2, { stage(0, 2, Bt, n0, kt2); stage(0, 3, Bt, n0 + 128, kt2); }, );
        PHASE(0, 3, , VM4);
        PHASE(1, 0, stage(0, 0, A,  m0,       kt2), );
        PHASE(1, 1, stage(0, 1, A,  m0 + 128, kt2), );
        PHASE(1, 2, { stage(1, 2, Bt, n0, kt3); stage(1, 3, Bt, n0 + 128, kt3); }, );
        PHASE(1, 3, , VM4);
    }
#undef PHASE
#undef VM4

    // epilogue — EXACT R4 order: mi-outer, nj-mid, jj-inner
    float cs[4] = {0.f, 0.f, 0.f, 0.f};
    #pragma unroll
    for (int mi = 0; mi < 8; ++mi) {
        const long rowb = m0 + wm * 128 + mi * 16 + cc * 4;
        #pragma unroll
        for (int nj = 0; nj < 4; ++nj) {
            const long col = n0 + wn * 64 + nj * 16 + rr;
            const float bv = bias[col];
            #pragma unroll
            for (int jj = 0; jj < 4; ++jj) {
                const float v = acc[mi][nj][jj] + bv;
                if (DO_COLSUM) cs[nj] += v;
                if (OUT_BF16) ((unsigned short*)C)[(rowb + jj) * N + col] = f2bf(v);
                else          ((float*)C)[(rowb + jj) * N + col] = v;
            }
        }
    }
    if (DO_COLSUM) {
        const int b = (int)(m0 >> 11);      // 2048 rows per batch
        #pragma unroll
        for (int nj = 0; nj < 4; ++nj) {
            float c0 = cs[nj];
            c0 += __shfl_xor(c0, 16, 64);
            c0 += __shfl_xor(c0, 32, 64);
            if (cc == 0)
                atomicAdd(totals + b * 1024 + n0 + wn * 64 + nj * 16 + rr, c0);
        }
    }
}

// ---------- 4. FSMN v4: burst-load window + taps in regs, 32 outputs/thread ----------
#define FS_ROWS 167   // 128 + 39
__global__ __launch_bounds__(256, 2) void k_fsmn(
    const unsigned short* __restrict__ p,   // (B*T, 1024) bf16
    const float* __restrict__ mw,           // (41, 1024) fp32
    const float* __restrict__ total,        // (B, 1024) fp32
    unsigned short* __restrict__ p2,        // (B*T, 1024) bf16
    int T)
{
    __shared__ unsigned short sp[FS_ROWS][64];   // [c][d], t = t0 + c - 39
    __shared__ float smw[41][64];
    const int b  = blockIdx.z;
    const int t0 = blockIdx.y * 128;
    const int d0 = blockIdx.x * 64;
    const int tid = threadIdx.x;

    for (int idx = tid; idx < 41 * 64; idx += 256) {
        int r = idx >> 6, c = idx & 63;
        smw[r][c] = mw[r * 1024 + d0 + c];
    }
    {
        const int row0 = tid >> 3;
        const int col8 = (tid & 7) * 8;
        #pragma unroll
        for (int i = 0; i < 6; ++i) {
            const int row = row0 + i * 32;
            if (row < FS_ROWS) {
                const int t = t0 + row - 39;
                u16x8 v = {0, 0, 0, 0, 0, 0, 0, 0};
                if (t >= 0)
                    v = *(const u16x8*)(p + ((long)b * T + t) * 1024 + d0 + col8);
                *(u16x8*)(&sp[row][col8]) = v;
            }
        }
    }
    __syncthreads();

    const int lane = tid & 63, wv = tid >> 6;
    const int d = d0 + lane;

    float m[40];
    #pragma unroll
    for (int l = 0; l < 40; ++l) m[l] = smw[l + 1][lane];
    const float m0v = smw[0][lane];
    const float tot = total[b * 1024 + d];

    #pragma unroll
    for (int pass = 0; pass < 2; ++pass) {
        const int obase = wv * 32 + pass * 16;
        float w[55];
        #pragma unroll
        for (int j = 0; j < 55; ++j) w[j] = bf2f(sp[obase + j][lane]);

        float acc[16];
        #pragma unroll
        for (int s = 0; s < 16; ++s) acc[s] = 0.f;
        #pragma unroll
        for (int lag = 0; lag < 40; ++lag) {
            const float mm = m[lag];
            #pragma unroll
            for (int s = 0; s < 16; ++s)
                acc[s] = fmaf(mm, w[s + 39 - lag], acc[s]);
        }

        float accw[16];
        {
            float S = 0.f;
            #pragma unroll
            for (int j = 0; j < 40; ++j) S += w[j];
            accw[0] = S;
            #pragma unroll
            for (int s = 1; s < 16; ++s) accw[s] = accw[s - 1] + w[s + 39] - w[s - 1];
        }

        unsigned short* ob = p2 + ((long)b * T + t0 + obase) * 1024 + d;
        #pragma unroll
        for (int s = 0; s < 16; ++s)
            ob[(long)s * 1024] = f2bf(acc[s] + m0v * (tot - accw[s]));
    }
}

// ---------- launch ----------
extern "C" void kernel_launch(void* const* d_in, const int* in_sizes, int n_in,
                              void* d_out, int out_size, void* d_ws, size_t ws_size,
                              hipStream_t stream) {
    const float* x  = (const float*)d_in[0];
    const float* W1 = (const float*)d_in[1];
    const float* b1 = (const float*)d_in[2];
    const float* W2 = (const float*)d_in[3];
    const float* b2 = (const float*)d_in[4];
    const float* mw = (const float*)d_in[5];
    float* out = (float*)d_out;

    const int B = 8, T = 2048;
    const long M = (long)B * T;          // 16384 rows
    const int N = 1024, K = 1024;

    char* ws = (char*)d_ws;
    unsigned short* x_bf   = (unsigned short*)(ws);
    unsigned short* W1t    = (unsigned short*)(ws + 33554432L);
    unsigned short* W2t    = (unsigned short*)(ws + 35651584L);
    unsigned short* p_bf   = (unsigned short*)(ws + 37748736L);
    float*          totals = (float*)(ws + 71303168L);
    unsigned short* p2_bf  = x_bf;

    k_cvt_bf16<<<2048, 256, 0, stream>>>(x, x_bf, M * 1024);

    k_transpose_bf16<<<dim3(16, 16, 2), 256, 0, stream>>>(W1, W1t, W2, W2t);

    hipMemsetAsync(totals, 0, B * 1024 * sizeof(float), stream);

    k_gemm256<1, 1><<<dim3((int)((M / 256) * (N / 256))), 512, 0, stream>>>(
        x_bf, W1t, b1, (void*)p_bf, totals, (int)M, N, K);

    k_fsmn<<<dim3(1024 / 64, T / 128, B), 256, 0, stream>>>(p_bf, mw, totals, p2_bf, T);

    k_gemm256<0, 0><<<dim3((int)((M / 256) * (N / 256))), 512, 0, stream>>>(
        p2_bf, W2t, b2, (void*)out, nullptr, (int)M, N, K);
}